// Round 10
// baseline (237.620 us; speedup 1.0000x reference)
//
#include <hip/hip_runtime.h>

// output element offsets (f32 elements)
#define OUT_X0   0
#define OUT_EMB  16777216
#define OUT_OPC  16781312
#define OUT_LOSS 16879616

// small-buffer byte offsets (relative to `small` base)
#define OFF_GFEAT 0            // 8192     u32 float-bits [16][128]
#define OFF_POOL  8192         // 65536    u32 float-bits [16][1024]
#define OFF_GCON  73728        // 65536    f32 [16][1024]
#define OFF_EMB   139264       // 16384    f32 [16][256]
#define OFF_HD1   155648       // 32768    f32 [16][512]
#define OFF_HD2   188416       // 65536    f32 [16][1024]
#define OFF_H3    253952       // 393216   f32 [16][6144]
#define OFF_OPC   647168       // 393216   f32 [16][6144]
#define OFF_D1M   1040384      // 262144   u32 [16][4096]
#define OFF_D2M   1302528      // 131072   u32 [16][2048]
#define OFF_PS    1433600      // 384      f32 [96]
#define OFF_W3BF  1433984      // 524288   bf16 w3 [1024][256]
#define H2_BYTES  (16u*1024*1024)   // bf16 h2 [65536][128] at ws+0 (big path)

typedef short short8 __attribute__((ext_vector_type(8)));
typedef float f32x4  __attribute__((ext_vector_type(4)));

__device__ __forceinline__ unsigned short f2bf(float f){
  unsigned u = __float_as_uint(f);
  return (unsigned short)((u + 0x7FFFu + ((u >> 16) & 1u)) >> 16);
}
__device__ __forceinline__ float bf2f(unsigned short h){
  return __uint_as_float(((unsigned)h) << 16);
}

// ------- conv1+conv2 (big path): h2 bf16 only + gfeat; one 64B store/thread -------
__global__ __launch_bounds__(256) void conv12_h2(
    const float* __restrict__ in_pc,
    const float* __restrict__ w1, const float* __restrict__ b1,
    const float* __restrict__ w2, const float* __restrict__ b2,
    unsigned short* __restrict__ h2b, unsigned* __restrict__ gfeatU)
{
  __shared__ unsigned gmax[32];
  int tid = threadIdx.x;
  if (tid < 32) gmax[tid] = 0u;
  __syncthreads();
  int idx = blockIdx.x*256 + tid;   // point id
  int b = idx >> 12;
  int gy = blockIdx.y;              // outputs [gy*32, gy*32+32)
  int lane = tid & 63;
  const float* p = in_pc + (size_t)idx*3;
  float px=p[0], py=p[1], pz=p[2];
  float h1[64];
  #pragma unroll
  for (int c=0;c<64;c++)
    h1[c] = fmaxf(w1[c*3]*px + w1[c*3+1]*py + w1[c*3+2]*pz + b1[c], 0.f);
  unsigned pk[16];
  #pragma unroll
  for (int jj=0;jj<16;jj++){
    int o0 = gy*32 + jj*2;
    float a0 = b2[o0], a1 = b2[o0+1];
    #pragma unroll
    for (int c=0;c<64;c++){
      a0 += w2[o0*64+c]*h1[c];
      a1 += w2[(o0+1)*64+c]*h1[c];
    }
    a0 = fmaxf(a0, 0.f); a1 = fmaxf(a1, 0.f);
    pk[jj] = (unsigned)f2bf(a0) | ((unsigned)f2bf(a1)<<16);
    float m0 = a0, m1 = a1;
    #pragma unroll
    for (int off=32; off; off>>=1){
      m0 = fmaxf(m0, __shfl_xor(m0, off));
      m1 = fmaxf(m1, __shfl_xor(m1, off));
    }
    if (lane==0){
      atomicMax(&gmax[jj*2],   __float_as_uint(m0));
      atomicMax(&gmax[jj*2+1], __float_as_uint(m1));
    }
  }
  uint4* dst = (uint4*)&h2b[(size_t)idx*128 + gy*32];
  dst[0] = make_uint4(pk[0], pk[1], pk[2], pk[3]);
  dst[1] = make_uint4(pk[4], pk[5], pk[6], pk[7]);
  dst[2] = make_uint4(pk[8], pk[9], pk[10], pk[11]);
  dst[3] = make_uint4(pk[12], pk[13], pk[14], pk[15]);
  __syncthreads();
  if (tid < 32) atomicMax(&gfeatU[b*128 + gy*32 + tid], gmax[tid]);
}

// ------- x0 build: transpose h2->x0 f32 (512) | gfeat bcast (8192) | gcon (4) -------
__global__ __launch_bounds__(256) void x0_expand(
    const unsigned short* __restrict__ h2b, const unsigned* __restrict__ gfeatU,
    float* __restrict__ x0, const float* __restrict__ w3,
    const float* __restrict__ b3, float* __restrict__ gcon)
{
  __shared__ unsigned short lt[128][132];
  int bid = blockIdx.x, tid = threadIdx.x;
  if (bid < 512){
    int nt = bid & 31, b = bid >> 5;          // 128-point tile
    const uint4* src = (const uint4*)(h2b + ((size_t)(b*4096 + nt*128))*128);
    #pragma unroll
    for (int i=0;i<8;i++){
      int idx = i*256 + tid;
      int pp = idx >> 4, cq = idx & 15;
      uint4 v = src[idx];
      *(uint4*)&lt[pp][cq*8] = v;
    }
    __syncthreads();
    int c = tid & 127, ng = tid >> 7;
    float* dst = x0 + ((size_t)(b*256 + c))*4096 + nt*128 + ng*64;
    #pragma unroll
    for (int n4=0;n4<16;n4++){
      float4 v;
      v.x = bf2f(lt[ng*64+n4*4+0][c]);
      v.y = bf2f(lt[ng*64+n4*4+1][c]);
      v.z = bf2f(lt[ng*64+n4*4+2][c]);
      v.w = bf2f(lt[ng*64+n4*4+3][c]);
      ((float4*)dst)[n4] = v;
    }
  } else if (bid < 8704){
    unsigned U = (bid-512)*256 + tid;   // over 16*128*1024 float4
    int n4 = U & 1023, c = (U >> 10) & 127, b = U >> 17;
    float g = __uint_as_float(gfeatU[b*128+c]);
    float4 v = {g,g,g,g};
    ((float4*)x0)[(((size_t)b*256 + 128 + c)*4096)/4 + n4] = v;
  } else {
    float* gf = (float*)lt;
    for (int i=tid;i<2048;i+=256) gf[i] = __uint_as_float(gfeatU[i]);
    __syncthreads();
    int o = (bid - 8704)*256 + tid;
    float bias = b3[o];
    float acc[16];
    #pragma unroll
    for (int b2i=0;b2i<16;b2i++) acc[b2i]=bias;
    for (int c=0;c<128;c++){
      float wv = w3[(size_t)o*256 + 128 + c];
      #pragma unroll
      for (int b2i=0;b2i<16;b2i++) acc[b2i] += gf[b2i*128+c]*wv;
    }
    #pragma unroll
    for (int b2i=0;b2i<16;b2i++) gcon[b2i*1024+o] = acc[b2i];
  }
}

// ---------------- w3 f32 -> bf16 pre-pass ----------------
__global__ __launch_bounds__(256) void w3_cvt(
    const float* __restrict__ w3, unsigned* __restrict__ w3bf)
{
  int i = blockIdx.x*256 + threadIdx.x;   // over 131072 float2
  float2 v = ((const float2*)w3)[i];
  w3bf[i] = (unsigned)f2bf(v.x) | ((unsigned)f2bf(v.y)<<16);
}

// ------- conv3 MFMA GEMM (256n x 128k)x(128k -> 1024o) + relu + max-pool -------
__global__ __launch_bounds__(512) void conv3_pool(
    const unsigned short* __restrict__ h2b, const unsigned short* __restrict__ w3b,
    const float* __restrict__ gcon, unsigned* __restrict__ pooled)
{
  __shared__ unsigned short Al[256*128];
  __shared__ unsigned short Bl[256*128];
  int mt = blockIdx.x, b = blockIdx.y;
  int tid = threadIdx.x;
  {
    const uint4* src = (const uint4*)(h2b + ((size_t)b*4096 + mt*256)*128);
    #pragma unroll
    for (int i=0;i<8;i++){
      int idx = i*512 + tid;
      int r = idx>>4, kc = idx&15;
      uint4 v = src[(size_t)r*16 + kc];
      int byte = (r*256 + kc*16) ^ ((r&7)<<4);
      *(uint4*)((char*)Al + byte) = v;
    }
  }
  int lane = tid & 63, wid = tid >> 6;
  int wm = wid >> 2, wn = wid & 3;
  int mbase = wm*128, nbase = wn*64;
  for (int nt=0; nt<4; nt++){
    if (nt) __syncthreads();
    {
      #pragma unroll
      for (int i=0;i<8;i++){
        int idx = i*512 + tid;
        int c = idx>>4, kc = idx&15;
        uint4 v = *(const uint4*)(w3b + ((size_t)(nt*256+c)*256 + kc*8));
        int byte = (c*256 + kc*16) ^ ((c&7)<<4);
        *(uint4*)((char*)Bl + byte) = v;
      }
    }
    __syncthreads();
    f32x4 acc[8][4] = {};
    #pragma unroll
    for (int ks=0;ks<4;ks++){
      int kb = (ks*32 + (lane>>4)*8)*2;
      short8 af[8], bfr[4];
      #pragma unroll
      for (int mi=0;mi<8;mi++){
        int row = mbase + mi*16 + (lane&15);
        af[mi] = *(const short8*)((const char*)Al + ((row*256 + kb) ^ ((row&7)<<4)));
      }
      #pragma unroll
      for (int ni=0;ni<4;ni++){
        int col = nbase + ni*16 + (lane&15);
        bfr[ni] = *(const short8*)((const char*)Bl + ((col*256 + kb) ^ ((col&7)<<4)));
      }
      #pragma unroll
      for (int mi=0;mi<8;mi++){
        #pragma unroll
        for (int ni=0;ni<4;ni++)
          acc[mi][ni] = __builtin_amdgcn_mfma_f32_16x16x32_bf16(af[mi], bfr[ni], acc[mi][ni], 0,0,0);
      }
    }
    #pragma unroll
    for (int ni=0;ni<4;ni++){
      int o = nt*256 + nbase + ni*16 + (lane&15);
      float g = gcon[b*1024 + o];
      float m = 0.f;
      #pragma unroll
      for (int mi=0;mi<8;mi++){
        f32x4 a = acc[mi][ni];
        #pragma unroll
        for (int r=0;r<4;r++){ float v = a[r]+g; m = fmaxf(m, v); }
      }
      m = fmaxf(m, 0.f);
      m = fmaxf(m, __shfl_xor(m, 16));
      m = fmaxf(m, __shfl_xor(m, 32));
      if (lane < 16) atomicMax(&pooled[(size_t)b*1024+o], __float_as_uint(m));
    }
  }
}

// ---- fallback (small ws): conv12 writes x0 f32 directly + gfeat ----
__global__ __launch_bounds__(256) void conv12_f32(
    const float* __restrict__ in_pc,
    const float* __restrict__ w1, const float* __restrict__ b1,
    const float* __restrict__ w2, const float* __restrict__ b2,
    float* __restrict__ x0, unsigned* __restrict__ gfeatU)
{
  __shared__ unsigned gmax[32];
  int tid = threadIdx.x;
  if (tid < 32) gmax[tid] = 0u;
  __syncthreads();
  int idx = blockIdx.x*256 + tid;
  int b = idx >> 12, n = idx & 4095;
  int gy = blockIdx.y;
  int lane = tid & 63;
  const float* p = in_pc + (size_t)idx*3;
  float px=p[0], py=p[1], pz=p[2];
  float h1[64];
  #pragma unroll
  for (int c=0;c<64;c++)
    h1[c] = fmaxf(w1[c*3]*px + w1[c*3+1]*py + w1[c*3+2]*pz + b1[c], 0.f);
  #pragma unroll
  for (int j=0;j<32;j++){
    int o = gy*32 + j;
    float a = b2[o];
    #pragma unroll
    for (int c=0;c<64;c++) a += w2[o*64+c]*h1[c];
    a = fmaxf(a, 0.f);
    x0[((size_t)b*256 + o)*4096 + n] = a;
    float m = a;
    #pragma unroll
    for (int off=32; off; off>>=1) m = fmaxf(m, __shfl_xor(m, off));
    if (lane==0) atomicMax(&gmax[j], __float_as_uint(m));
  }
  __syncthreads();
  if (tid < 32) atomicMax(&gfeatU[b*128 + gy*32 + tid], gmax[tid]);
}

// ---- fallback: gfeat bcast + gcon ----
__global__ __launch_bounds__(256) void bcast_gcon(
    const unsigned* __restrict__ gfeatU, float* __restrict__ x0,
    const float* __restrict__ w3, const float* __restrict__ b3,
    float* __restrict__ gcon)
{
  __shared__ float gf[2048];
  int tid = threadIdx.x;
  if (blockIdx.x < 8192){
    unsigned U = blockIdx.x*256 + tid;
    int n4 = U & 1023, c = (U >> 10) & 127, b = U >> 17;
    float g = __uint_as_float(gfeatU[b*128+c]);
    float4 v = {g,g,g,g};
    ((float4*)x0)[(((size_t)b*256 + 128 + c)*4096)/4 + n4] = v;
  } else {
    for (int i=tid;i<2048;i+=256) gf[i] = __uint_as_float(gfeatU[i]);
    __syncthreads();
    int o = (blockIdx.x - 8192)*256 + tid;
    float bias = b3[o];
    float acc[16];
    #pragma unroll
    for (int b=0;b<16;b++) acc[b]=bias;
    for (int c=0;c<128;c++){
      float wv = w3[(size_t)o*256 + 128 + c];
      #pragma unroll
      for (int b=0;b<16;b++) acc[b] += gf[b*128+c]*wv;
    }
    #pragma unroll
    for (int b=0;b<16;b++) gcon[b*1024+o] = acc[b];
  }
}

// ---- fallback conv3 ----
__global__ __launch_bounds__(256) void conv3n(
    const float* __restrict__ x0, const unsigned* __restrict__ gfeatU,
    const float* __restrict__ w3, const float* __restrict__ b3,
    unsigned* __restrict__ pooled)
{
  __shared__ float wrow[8][256];
  int b = blockIdx.x >> 7, og = (blockIdx.x & 127)*8, tid = threadIdx.x;
  for (int i=tid;i<2048;i+=256){ int j=i>>8, c=i&255; wrow[j][c]=w3[(size_t)(og+j)*256+c]; }
  __syncthreads();
  float gconst[8];
  #pragma unroll
  for (int j=0;j<8;j++){
    float g = b3[og+j];
    for (int c=0;c<128;c++) g += __uint_as_float(gfeatU[b*128+c])*wrow[j][128+c];
    gconst[j] = g;
  }
  const float* xb = x0 + (size_t)b*256*4096;
  float m[8];
  #pragma unroll
  for (int j=0;j<8;j++) m[j]=0.f;
  for (int n=tid;n<4096;n+=256){
    float v[8];
    #pragma unroll
    for (int j=0;j<8;j++) v[j]=gconst[j];
    for (int c=0;c<128;c++){
      float xv = xb[(size_t)c*4096 + n];
      #pragma unroll
      for (int j=0;j<8;j++) v[j] += xv*wrow[j][c];
    }
    #pragma unroll
    for (int j=0;j<8;j++) m[j] = fmaxf(m[j], v[j]);
  }
  #pragma unroll
  for (int j=0;j<8;j++){
    float v = m[j];
    for (int off=32; off; off>>=1) v = fmaxf(v, __shfl_xor(v, off));
    if ((tid&63)==0) atomicMax(&pooled[(size_t)b*1024+og+j], __float_as_uint(v));
  }
}

// ------- fc: one wave per output o, all 16 batches in registers -------
template<bool RELU>
__global__ __launch_bounds__(256) void fc_wave16(
    const float* __restrict__ A, const float* __restrict__ W,
    const float* __restrict__ bias, float* __restrict__ out,
    float* __restrict__ out2, int K, int O)
{
  int lane = threadIdx.x & 63, w = threadIdx.x >> 6;
  int o = blockIdx.x*4 + w;
  const float* Wr = W + (size_t)o*K;
  float acc[16];
  #pragma unroll
  for (int b=0;b<16;b++) acc[b]=0.f;
  for (int k = lane*4; k < K; k += 256){
    float4 wv = *(const float4*)&Wr[k];
    #pragma unroll
    for (int b=0;b<16;b++){
      float4 av = *(const float4*)&A[(size_t)b*K + k];
      acc[b] += wv.x*av.x + wv.y*av.y + wv.z*av.z + wv.w*av.w;
    }
  }
  #pragma unroll
  for (int b=0;b<16;b++){
    float v = acc[b];
    #pragma unroll
    for (int off=32; off; off>>=1) v += __shfl_xor(v, off);
    if (lane==0){
      v += bias[o];
      if (RELU) v = fmaxf(v, 0.f);
      out[(size_t)b*O+o] = v;
      if (out2) out2[(size_t)b*O+o] = v;
    }
  }
}

// ---------------- LayerNorm over 6144 per batch row ----------------
__global__ __launch_bounds__(256) void lnorm(
    const float* __restrict__ h3, const float* __restrict__ g,
    const float* __restrict__ be, float* __restrict__ outf,
    float* __restrict__ outb)
{
  int b = blockIdx.x, tid = threadIdx.x;
  const float* x = h3 + b*6144;
  float s=0.f, s2=0.f;
  for (int i=tid;i<6144;i+=256){ float v=x[i]; s+=v; s2+=v*v; }
  for (int off=32; off; off>>=1){ s += __shfl_xor(s,off); s2 += __shfl_xor(s2,off); }
  __shared__ float red[8];
  int lane = tid&63, wid = tid>>6;
  if (lane==0){ red[wid]=s; red[4+wid]=s2; }
  __syncthreads();
  s  = red[0]+red[1]+red[2]+red[3];
  s2 = red[4]+red[5]+red[6]+red[7];
  float mu  = s * (1.f/6144.f);
  float var = s2 * (1.f/6144.f) - mu*mu;
  float inv = rsqrtf(var + 1e-5f);
  for (int i=tid;i<6144;i+=256){
    float v = (x[i]-mu)*inv*g[i] + be[i];
    outf[b*6144+i] = v;
    outb[b*6144+i] = v;
  }
}

#define DIST(mn, qx_,qy_,qz_, X_,Y_,Z_) { \
  float dx=qx_-X_, dy=qy_-Y_, dz=qz_-Z_; \
  float d=dx*dx+dy*dy+dz*dz; mn=fminf(mn,d); }

// ---- chamfer merged: d1 (blocks 0..511, 2 pts/thread) + d2 (512..767) ----
__global__ __launch_bounds__(256) void chamfer_all(
    const float* __restrict__ in_pc, const float* __restrict__ opc,
    unsigned* __restrict__ d1m, unsigned* __restrict__ d2m)
{
  __shared__ float sb[3072];
  int bid = blockIdx.x, tid = threadIdx.x;
  if (bid < 512){
    int xt = bid & 7, b = (bid>>3) & 15, mt = bid >> 7;   // 8 n-chunks x 16 b x 4 mt
    float *qx=sb, *qy=sb+512, *qz=sb+1024;
    const float* qb = opc + b*6144 + mt*1536;
    for (int i=tid;i<512;i+=256){ qx[i]=qb[i*3]; qy[i]=qb[i*3+1]; qz[i]=qb[i*3+2]; }
    __syncthreads();
    int n0 = xt*512 + tid, n1 = n0 + 256;
    const float* P = in_pc + (size_t)b*4096*3;
    float p0x=P[n0*3], p0y=P[n0*3+1], p0z=P[n0*3+2];
    float p1x=P[n1*3], p1y=P[n1*3+1], p1z=P[n1*3+2];
    float mn0=3e38f, mn1=3e38f;
    for (int m4=0;m4<128;m4++){
      float4 X=*(const float4*)&qx[m4*4];
      float4 Y=*(const float4*)&qy[m4*4];
      float4 Z=*(const float4*)&qz[m4*4];
      DIST(mn0,p0x,p0y,p0z,X.x,Y.x,Z.x); DIST(mn1,p1x,p1y,p1z,X.x,Y.x,Z.x);
      DIST(mn0,p0x,p0y,p0z,X.y,Y.y,Z.y); DIST(mn1,p1x,p1y,p1z,X.y,Y.y,Z.y);
      DIST(mn0,p0x,p0y,p0z,X.z,Y.z,Z.z); DIST(mn1,p1x,p1y,p1z,X.z,Y.z,Z.z);
      DIST(mn0,p0x,p0y,p0z,X.w,Y.w,Z.w); DIST(mn1,p1x,p1y,p1z,X.w,Y.w,Z.w);
    }
    atomicMin(&d1m[b*4096+n0], __float_as_uint(mn0));
    atomicMin(&d1m[b*4096+n1], __float_as_uint(mn1));
  } else {
    int r = bid - 512;
    int xt = r & 3, b = (r>>2) & 15, nt = r >> 6;   // 4 m-chunks x 16 b x 4 nt
    float *sx=sb, *sy=sb+1024, *sz=sb+2048;
    size_t base = ((size_t)b*4096 + nt*1024)*3;
    for (int i=tid;i<1024;i+=256){
      sx[i]=in_pc[base+i*3]; sy[i]=in_pc[base+i*3+1]; sz[i]=in_pc[base+i*3+2];
    }
    __syncthreads();
    int m0 = xt*512 + tid, m1 = m0 + 256;
    const float* Q = opc + b*6144;
    float q0x=Q[m0*3], q0y=Q[m0*3+1], q0z=Q[m0*3+2];
    float q1x=Q[m1*3], q1y=Q[m1*3+1], q1z=Q[m1*3+2];
    float mn0=3e38f, mn1=3e38f;
    for (int n4=0;n4<256;n4++){
      float4 X=*(const float4*)&sx[n4*4];
      float4 Y=*(const float4*)&sy[n4*4];
      float4 Z=*(const float4*)&sz[n4*4];
      DIST(mn0,q0x,q0y,q0z,X.x,Y.x,Z.x); DIST(mn1,q1x,q1y,q1z,X.x,Y.x,Z.x);
      DIST(mn0,q0x,q0y,q0z,X.y,Y.y,Z.y); DIST(mn1,q1x,q1y,q1z,X.y,Y.y,Z.y);
      DIST(mn0,q0x,q0y,q0z,X.z,Y.z,Z.z); DIST(mn1,q1x,q1y,q1z,X.z,Y.z,Z.z);
      DIST(mn0,q0x,q0y,q0z,X.w,Y.w,Z.w); DIST(mn1,q1x,q1y,q1z,X.w,Y.w,Z.w);
    }
    atomicMin(&d2m[b*2048+m0], __float_as_uint(mn0));
    atomicMin(&d2m[b*2048+m1], __float_as_uint(mn1));
  }
}

// ---------------- deterministic loss reduction ----------------
__global__ __launch_bounds__(256) void sum_part(
    const unsigned* __restrict__ d1m, const unsigned* __restrict__ d2m,
    float* __restrict__ ps)
{
  int bid = blockIdx.x, tid = threadIdx.x;
  const unsigned* src = (bid<64) ? (d1m + bid*1024) : (d2m + (size_t)(bid-64)*1024);
  float s = 0.f;
  for (int i=tid;i<1024;i+=256) s += __uint_as_float(src[i]);
  for (int off=32; off; off>>=1) s += __shfl_xor(s,off);
  __shared__ float red[4];
  if ((tid&63)==0) red[tid>>6]=s;
  __syncthreads();
  if (tid==0) ps[bid] = red[0]+red[1]+red[2]+red[3];
}

__global__ void loss_k(const float* __restrict__ ps, float* __restrict__ out){
  int tid = threadIdx.x;  // 128 threads
  float v = 0.f;
  if (tid < 64) v = ps[tid] * (1.0f/65536.0f);
  else if (tid < 96) v = ps[tid] * (1.0f/32768.0f);
  for (int off=32; off; off>>=1) v += __shfl_xor(v,off);
  __shared__ float red[2];
  if ((tid&63)==0) red[tid>>6]=v;
  __syncthreads();
  if (tid==0) out[0] = red[0]+red[1];
}

// ---------------- launch ----------------
extern "C" void kernel_launch(void* const* d_in, const int* in_sizes, int n_in,
                              void* d_out, int out_size, void* d_ws, size_t ws_size,
                              hipStream_t stream)
{
  (void)in_sizes; (void)n_in; (void)out_size;
  const float* in_pc = (const float*)d_in[0];
  const float* w1   = (const float*)d_in[1];
  const float* b1   = (const float*)d_in[2];
  const float* w2   = (const float*)d_in[3];
  const float* b2   = (const float*)d_in[4];
  const float* w3   = (const float*)d_in[5];
  const float* b3   = (const float*)d_in[6];
  const float* wenc = (const float*)d_in[7];
  const float* benc = (const float*)d_in[8];
  const float* wf1  = (const float*)d_in[9];
  const float* bfc1 = (const float*)d_in[10];
  const float* wf2  = (const float*)d_in[11];
  const float* bfc2 = (const float*)d_in[12];
  const float* wf3  = (const float*)d_in[13];
  const float* bfc3 = (const float*)d_in[14];
  const float* lng  = (const float*)d_in[15];
  const float* lnb  = (const float*)d_in[16];
  float* out = (float*)d_out;

  bool big = ws_size >= (size_t)(H2_BYTES + 2*1024*1024);
  char* ws = (char*)d_ws;
  unsigned short* h2b = (unsigned short*)ws;
  char* small = ws + (big ? H2_BYTES : 0);

  unsigned* gfeatU = (unsigned*)(small + OFF_GFEAT);
  float* pooled = (float*)(small + OFF_POOL);
  float* gcon = (float*)(small + OFF_GCON);
  float* emb  = (float*)(small + OFF_EMB);
  float* hd1  = (float*)(small + OFF_HD1);
  float* hd2  = (float*)(small + OFF_HD2);
  float* h3   = (float*)(small + OFF_H3);
  float* opc  = (float*)(small + OFF_OPC);
  unsigned* d1m = (unsigned*)(small + OFF_D1M);
  unsigned* d2m = (unsigned*)(small + OFF_D2M);
  float* ps   = (float*)(small + OFF_PS);
  unsigned short* w3b = (unsigned short*)(small + OFF_W3BF);

  hipMemsetAsync(small + OFF_GFEAT, 0, 8192 + 65536, stream);      // gfeat + pooled = 0
  hipMemsetAsync(small + OFF_D1M, 0x7F, 262144 + 131072, stream);  // d1m + d2m ~ +inf

  if (big){
    w3_cvt<<<512, 256, 0, stream>>>(w3, (unsigned*)w3b);
    conv12_h2<<<dim3(256,4), 256, 0, stream>>>(in_pc, w1, b1, w2, b2, h2b, gfeatU);
    x0_expand<<<8708, 256, 0, stream>>>(h2b, gfeatU, out, w3, b3, gcon);
    conv3_pool<<<dim3(16,16), 512, 0, stream>>>(h2b, w3b, gcon, (unsigned*)pooled);
  } else {
    conv12_f32<<<dim3(256,4), 256, 0, stream>>>(in_pc, w1, b1, w2, b2, out, gfeatU);
    bcast_gcon<<<8196, 256, 0, stream>>>(gfeatU, out, w3, b3, gcon);
    conv3n<<<2048, 256, 0, stream>>>(out, gfeatU, w3, b3, (unsigned*)pooled);
  }
  fc_wave16<false><<<64,   256, 0, stream>>>(pooled, wenc, benc, emb, out + OUT_EMB, 1024, 256);
  fc_wave16<true ><<<128,  256, 0, stream>>>(emb, wf1, bfc1, hd1, nullptr, 256, 512);
  fc_wave16<true ><<<256,  256, 0, stream>>>(hd1, wf2, bfc2, hd2, nullptr, 512, 1024);
  fc_wave16<false><<<1536, 256, 0, stream>>>(hd2, wf3, bfc3, h3, nullptr, 1024, 6144);
  lnorm<<<16, 256, 0, stream>>>(h3, lng, lnb, opc, out + OUT_OPC);
  chamfer_all<<<768, 256, 0, stream>>>(in_pc, opc, d1m, d2m);
  sum_part<<<96, 256, 0, stream>>>(d1m, d2m, ps);
  loss_k<<<1, 128, 0, stream>>>(ps, out + OUT_LOSS);
}

// Round 11
// 189.147 us; speedup vs baseline: 1.2563x; 1.2563x over previous
//
#include <hip/hip_runtime.h>

// output element offsets (f32 elements)
#define OUT_X0   0
#define OUT_EMB  16777216
#define OUT_OPC  16781312
#define OUT_LOSS 16879616

// small-buffer byte offsets (relative to `small` base)
#define OFF_GFEAT 0            // 8192     u32 float-bits [16][128]
#define OFF_POOL  8192         // 65536    u32 float-bits [16][1024]
#define OFF_GCON  73728        // 65536    f32 [16][1024]
#define OFF_EMB   139264       // 16384    f32 [16][256]
#define OFF_HD1   155648       // 32768    f32 [16][512]
#define OFF_HD2   188416       // 65536    f32 [16][1024]
#define OFF_H3    253952       // 393216   f32 [16][6144]
#define OFF_OPC   647168       // 393216   f32 [16][6144]
#define OFF_D1M   1040384      // 262144   u32 [16][4096]
#define OFF_D2M   1302528      // 131072   u32 [16][2048]
#define OFF_PS    1433600      // 384      f32 [96]
#define OFF_W3BF  1433984      // 524288   bf16 w3 [1024][256]
#define H2_BYTES  (16u*1024*1024)   // bf16 h2 [65536][128] at ws+0 (big path)

typedef short short8 __attribute__((ext_vector_type(8)));
typedef float f32x4  __attribute__((ext_vector_type(4)));

__device__ __forceinline__ unsigned short f2bf(float f){
  unsigned u = __float_as_uint(f);
  return (unsigned short)((u + 0x7FFFu + ((u >> 16) & 1u)) >> 16);
}

// ------- conv1+conv2 (big): x0 f32 [c][n] + h2 bf16 [n][c] + gfeat, one pass -------
__global__ __launch_bounds__(256) void conv12_full(
    const float* __restrict__ in_pc,
    const float* __restrict__ w1, const float* __restrict__ b1,
    const float* __restrict__ w2, const float* __restrict__ b2,
    float* __restrict__ x0, unsigned short* __restrict__ h2b,
    unsigned* __restrict__ gfeatU)
{
  __shared__ unsigned gmax[32];
  int tid = threadIdx.x;
  if (tid < 32) gmax[tid] = 0u;
  __syncthreads();
  int idx = blockIdx.x*256 + tid;   // point id
  int b = idx >> 12, n = idx & 4095;
  int gy = blockIdx.y;              // outputs [gy*32, gy*32+32)
  int lane = tid & 63;
  const float* p = in_pc + (size_t)idx*3;
  float px=p[0], py=p[1], pz=p[2];
  float h1[64];
  #pragma unroll
  for (int c=0;c<64;c++)
    h1[c] = fmaxf(w1[c*3]*px + w1[c*3+1]*py + w1[c*3+2]*pz + b1[c], 0.f);
  unsigned pk[16];
  float* xb = x0 + ((size_t)b*256 + gy*32)*4096 + n;
  #pragma unroll
  for (int jj=0;jj<16;jj++){
    int o0 = gy*32 + jj*2;
    float a0 = b2[o0], a1 = b2[o0+1];
    #pragma unroll
    for (int c=0;c<64;c++){
      a0 += w2[o0*64+c]*h1[c];
      a1 += w2[(o0+1)*64+c]*h1[c];
    }
    a0 = fmaxf(a0, 0.f); a1 = fmaxf(a1, 0.f);
    xb[(size_t)(jj*2)*4096]   = a0;           // 256B/wave contiguous, full lines
    xb[(size_t)(jj*2+1)*4096] = a1;
    pk[jj] = (unsigned)f2bf(a0) | ((unsigned)f2bf(a1)<<16);
    float m0 = a0, m1 = a1;
    #pragma unroll
    for (int off=32; off; off>>=1){
      m0 = fmaxf(m0, __shfl_xor(m0, off));
      m1 = fmaxf(m1, __shfl_xor(m1, off));
    }
    if (lane==0){
      atomicMax(&gmax[jj*2],   __float_as_uint(m0));
      atomicMax(&gmax[jj*2+1], __float_as_uint(m1));
    }
  }
  uint4* dst = (uint4*)&h2b[(size_t)idx*128 + gy*32];   // 64B adjacent -> merged
  dst[0] = make_uint4(pk[0], pk[1], pk[2], pk[3]);
  dst[1] = make_uint4(pk[4], pk[5], pk[6], pk[7]);
  dst[2] = make_uint4(pk[8], pk[9], pk[10], pk[11]);
  dst[3] = make_uint4(pk[12], pk[13], pk[14], pk[15]);
  __syncthreads();
  if (tid < 32) atomicMax(&gfeatU[b*128 + gy*32 + tid], gmax[tid]);
}

// ---- gfeat bcast (8192 blocks) + gcon (4 blocks) ----
__global__ __launch_bounds__(256) void bcast_gcon(
    const unsigned* __restrict__ gfeatU, float* __restrict__ x0,
    const float* __restrict__ w3, const float* __restrict__ b3,
    float* __restrict__ gcon)
{
  __shared__ float gf[2048];
  int tid = threadIdx.x;
  if (blockIdx.x < 8192){
    unsigned U = blockIdx.x*256 + tid;
    int n4 = U & 1023, c = (U >> 10) & 127, b = U >> 17;
    float g = __uint_as_float(gfeatU[b*128+c]);
    float4 v = {g,g,g,g};
    ((float4*)x0)[(((size_t)b*256 + 128 + c)*4096)/4 + n4] = v;
  } else {
    for (int i=tid;i<2048;i+=256) gf[i] = __uint_as_float(gfeatU[i]);
    __syncthreads();
    int o = (blockIdx.x - 8192)*256 + tid;
    float bias = b3[o];
    float acc[16];
    #pragma unroll
    for (int b=0;b<16;b++) acc[b]=bias;
    for (int c=0;c<128;c++){
      float wv = w3[(size_t)o*256 + 128 + c];
      #pragma unroll
      for (int b=0;b<16;b++) acc[b] += gf[b*128+c]*wv;
    }
    #pragma unroll
    for (int b=0;b<16;b++) gcon[b*1024+o] = acc[b];
  }
}

// ---------------- w3 f32 -> bf16 pre-pass ----------------
__global__ __launch_bounds__(256) void w3_cvt(
    const float* __restrict__ w3, unsigned* __restrict__ w3bf)
{
  int i = blockIdx.x*256 + threadIdx.x;   // over 131072 float2
  float2 v = ((const float2*)w3)[i];
  w3bf[i] = (unsigned)f2bf(v.x) | ((unsigned)f2bf(v.y)<<16);
}

// ------- conv3 MFMA GEMM (256n x 128k)x(128k -> 1024o) + relu + max-pool -------
__global__ __launch_bounds__(512) void conv3_pool(
    const unsigned short* __restrict__ h2b, const unsigned short* __restrict__ w3b,
    const float* __restrict__ gcon, unsigned* __restrict__ pooled)
{
  __shared__ unsigned short Al[256*128];
  __shared__ unsigned short Bl[256*128];
  int mt = blockIdx.x, b = blockIdx.y;
  int tid = threadIdx.x;
  {
    const uint4* src = (const uint4*)(h2b + ((size_t)b*4096 + mt*256)*128);
    #pragma unroll
    for (int i=0;i<8;i++){
      int idx = i*512 + tid;
      int r = idx>>4, kc = idx&15;
      uint4 v = src[(size_t)r*16 + kc];
      int byte = (r*256 + kc*16) ^ ((r&7)<<4);
      *(uint4*)((char*)Al + byte) = v;
    }
  }
  int lane = tid & 63, wid = tid >> 6;
  int wm = wid >> 2, wn = wid & 3;
  int mbase = wm*128, nbase = wn*64;
  for (int nt=0; nt<4; nt++){
    if (nt) __syncthreads();
    {
      #pragma unroll
      for (int i=0;i<8;i++){
        int idx = i*512 + tid;
        int c = idx>>4, kc = idx&15;
        uint4 v = *(const uint4*)(w3b + ((size_t)(nt*256+c)*256 + kc*8));
        int byte = (c*256 + kc*16) ^ ((c&7)<<4);
        *(uint4*)((char*)Bl + byte) = v;
      }
    }
    __syncthreads();
    f32x4 acc[8][4] = {};
    #pragma unroll
    for (int ks=0;ks<4;ks++){
      int kb = (ks*32 + (lane>>4)*8)*2;
      short8 af[8], bfr[4];
      #pragma unroll
      for (int mi=0;mi<8;mi++){
        int row = mbase + mi*16 + (lane&15);
        af[mi] = *(const short8*)((const char*)Al + ((row*256 + kb) ^ ((row&7)<<4)));
      }
      #pragma unroll
      for (int ni=0;ni<4;ni++){
        int col = nbase + ni*16 + (lane&15);
        bfr[ni] = *(const short8*)((const char*)Bl + ((col*256 + kb) ^ ((col&7)<<4)));
      }
      #pragma unroll
      for (int mi=0;mi<8;mi++){
        #pragma unroll
        for (int ni=0;ni<4;ni++)
          acc[mi][ni] = __builtin_amdgcn_mfma_f32_16x16x32_bf16(af[mi], bfr[ni], acc[mi][ni], 0,0,0);
      }
    }
    #pragma unroll
    for (int ni=0;ni<4;ni++){
      int o = nt*256 + nbase + ni*16 + (lane&15);
      float g = gcon[b*1024 + o];
      float m = 0.f;
      #pragma unroll
      for (int mi=0;mi<8;mi++){
        f32x4 a = acc[mi][ni];
        #pragma unroll
        for (int r=0;r<4;r++){ float v = a[r]+g; m = fmaxf(m, v); }
      }
      m = fmaxf(m, 0.f);
      m = fmaxf(m, __shfl_xor(m, 16));
      m = fmaxf(m, __shfl_xor(m, 32));
      if (lane < 16) atomicMax(&pooled[(size_t)b*1024+o], __float_as_uint(m));
    }
  }
}

// ---- fallback (small ws): conv12 writes x0 f32 directly + gfeat ----
__global__ __launch_bounds__(256) void conv12_f32(
    const float* __restrict__ in_pc,
    const float* __restrict__ w1, const float* __restrict__ b1,
    const float* __restrict__ w2, const float* __restrict__ b2,
    float* __restrict__ x0, unsigned* __restrict__ gfeatU)
{
  __shared__ unsigned gmax[32];
  int tid = threadIdx.x;
  if (tid < 32) gmax[tid] = 0u;
  __syncthreads();
  int idx = blockIdx.x*256 + tid;
  int b = idx >> 12, n = idx & 4095;
  int gy = blockIdx.y;
  int lane = tid & 63;
  const float* p = in_pc + (size_t)idx*3;
  float px=p[0], py=p[1], pz=p[2];
  float h1[64];
  #pragma unroll
  for (int c=0;c<64;c++)
    h1[c] = fmaxf(w1[c*3]*px + w1[c*3+1]*py + w1[c*3+2]*pz + b1[c], 0.f);
  #pragma unroll
  for (int j=0;j<32;j++){
    int o = gy*32 + j;
    float a = b2[o];
    #pragma unroll
    for (int c=0;c<64;c++) a += w2[o*64+c]*h1[c];
    a = fmaxf(a, 0.f);
    x0[((size_t)b*256 + o)*4096 + n] = a;
    float m = a;
    #pragma unroll
    for (int off=32; off; off>>=1) m = fmaxf(m, __shfl_xor(m, off));
    if (lane==0) atomicMax(&gmax[j], __float_as_uint(m));
  }
  __syncthreads();
  if (tid < 32) atomicMax(&gfeatU[b*128 + gy*32 + tid], gmax[tid]);
}

// ---- fallback conv3 ----
__global__ __launch_bounds__(256) void conv3n(
    const float* __restrict__ x0, const unsigned* __restrict__ gfeatU,
    const float* __restrict__ w3, const float* __restrict__ b3,
    unsigned* __restrict__ pooled)
{
  __shared__ float wrow[8][256];
  int b = blockIdx.x >> 7, og = (blockIdx.x & 127)*8, tid = threadIdx.x;
  for (int i=tid;i<2048;i+=256){ int j=i>>8, c=i&255; wrow[j][c]=w3[(size_t)(og+j)*256+c]; }
  __syncthreads();
  float gconst[8];
  #pragma unroll
  for (int j=0;j<8;j++){
    float g = b3[og+j];
    for (int c=0;c<128;c++) g += __uint_as_float(gfeatU[b*128+c])*wrow[j][128+c];
    gconst[j] = g;
  }
  const float* xb = x0 + (size_t)b*256*4096;
  float m[8];
  #pragma unroll
  for (int j=0;j<8;j++) m[j]=0.f;
  for (int n=tid;n<4096;n+=256){
    float v[8];
    #pragma unroll
    for (int j=0;j<8;j++) v[j]=gconst[j];
    for (int c=0;c<128;c++){
      float xv = xb[(size_t)c*4096 + n];
      #pragma unroll
      for (int j=0;j<8;j++) v[j] += xv*wrow[j][c];
    }
    #pragma unroll
    for (int j=0;j<8;j++) m[j] = fmaxf(m[j], v[j]);
  }
  #pragma unroll
  for (int j=0;j<8;j++){
    float v = m[j];
    for (int off=32; off; off>>=1) v = fmaxf(v, __shfl_xor(v, off));
    if ((tid&63)==0) atomicMax(&pooled[(size_t)b*1024+og+j], __float_as_uint(v));
  }
}

// ------- fc: one wave per output o, all 16 batches in registers -------
template<bool RELU>
__global__ __launch_bounds__(256) void fc_wave16(
    const float* __restrict__ A, const float* __restrict__ W,
    const float* __restrict__ bias, float* __restrict__ out,
    float* __restrict__ out2, int K, int O)
{
  int lane = threadIdx.x & 63, w = threadIdx.x >> 6;
  int o = blockIdx.x*4 + w;
  const float* Wr = W + (size_t)o*K;
  float acc[16];
  #pragma unroll
  for (int b=0;b<16;b++) acc[b]=0.f;
  for (int k = lane*4; k < K; k += 256){
    float4 wv = *(const float4*)&Wr[k];
    #pragma unroll
    for (int b=0;b<16;b++){
      float4 av = *(const float4*)&A[(size_t)b*K + k];
      acc[b] += wv.x*av.x + wv.y*av.y + wv.z*av.z + wv.w*av.w;
    }
  }
  #pragma unroll
  for (int b=0;b<16;b++){
    float v = acc[b];
    #pragma unroll
    for (int off=32; off; off>>=1) v += __shfl_xor(v, off);
    if (lane==0){
      v += bias[o];
      if (RELU) v = fmaxf(v, 0.f);
      out[(size_t)b*O+o] = v;
      if (out2) out2[(size_t)b*O+o] = v;
    }
  }
}

// ---------------- LayerNorm over 6144 per batch row ----------------
__global__ __launch_bounds__(256) void lnorm(
    const float* __restrict__ h3, const float* __restrict__ g,
    const float* __restrict__ be, float* __restrict__ outf,
    float* __restrict__ outb)
{
  int b = blockIdx.x, tid = threadIdx.x;
  const float* x = h3 + b*6144;
  float s=0.f, s2=0.f;
  for (int i=tid;i<6144;i+=256){ float v=x[i]; s+=v; s2+=v*v; }
  for (int off=32; off; off>>=1){ s += __shfl_xor(s,off); s2 += __shfl_xor(s2,off); }
  __shared__ float red[8];
  int lane = tid&63, wid = tid>>6;
  if (lane==0){ red[wid]=s; red[4+wid]=s2; }
  __syncthreads();
  s  = red[0]+red[1]+red[2]+red[3];
  s2 = red[4]+red[5]+red[6]+red[7];
  float mu  = s * (1.f/6144.f);
  float var = s2 * (1.f/6144.f) - mu*mu;
  float inv = rsqrtf(var + 1e-5f);
  for (int i=tid;i<6144;i+=256){
    float v = (x[i]-mu)*inv*g[i] + be[i];
    outf[b*6144+i] = v;
    outb[b*6144+i] = v;
  }
}

// ---- chamfer v3: 1 query/thread, q^2-2pq decomposition (5 ops/pair) ----
// blocks 0..2047: d1 (16 n-chunks x 16 b x 8 m-chunks)
// blocks 2048..4095: d2 (8 m-chunks x 16 b x 16 n-chunks)
__global__ __launch_bounds__(256) void chamfer_all(
    const float* __restrict__ in_pc, const float* __restrict__ opc,
    unsigned* __restrict__ d1m, unsigned* __restrict__ d2m)
{
  __shared__ float sx[256], sy[256], sz[256], s2[256];
  int bid = blockIdx.x, tid = threadIdx.x;
  const float* stage;
  const float* qry;
  unsigned* outp;
  if (bid < 2048){
    int xt = bid & 15, b = (bid >> 4) & 15, mt = bid >> 8;
    stage = opc + b*6144 + mt*768;
    qry   = in_pc + ((size_t)b*4096 + xt*256 + tid)*3;
    outp  = d1m + b*4096 + xt*256 + tid;
  } else {
    int r = bid - 2048;
    int xt = r & 7, b = (r >> 3) & 15, nt = r >> 7;
    stage = in_pc + ((size_t)b*4096 + nt*256)*3;
    qry   = opc + b*6144 + (xt*256 + tid)*3;
    outp  = d2m + b*2048 + xt*256 + tid;
  }
  {
    const float* S = stage + tid*3;
    float x=S[0], y=S[1], z=S[2];
    sx[tid]=x; sy[tid]=y; sz[tid]=z; s2[tid]=x*x+y*y+z*z;
  }
  __syncthreads();
  float qx=qry[0], qy=qry[1], qz=qry[2];
  float p2 = qx*qx + qy*qy + qz*qz;
  float ma=3.0e38f, mb=3.0e38f;
  #pragma unroll 2
  for (int i=0;i<64;i++){
    float4 X  = *(const float4*)&sx[i*4];
    float4 Y  = *(const float4*)&sy[i*4];
    float4 Z  = *(const float4*)&sz[i*4];
    float4 Q2 = *(const float4*)&s2[i*4];
    float t;
    t = fmaf(-2.f, fmaf(qx,X.x,fmaf(qy,Y.x,qz*Z.x)), Q2.x); ma = fminf(ma,t);
    t = fmaf(-2.f, fmaf(qx,X.y,fmaf(qy,Y.y,qz*Z.y)), Q2.y); mb = fminf(mb,t);
    t = fmaf(-2.f, fmaf(qx,X.z,fmaf(qy,Y.z,qz*Z.z)), Q2.z); ma = fminf(ma,t);
    t = fmaf(-2.f, fmaf(qx,X.w,fmaf(qy,Y.w,qz*Z.w)), Q2.w); mb = fminf(mb,t);
  }
  float d = fmaxf(p2 + fminf(ma, mb), 0.f);
  atomicMin(outp, __float_as_uint(d));
}

// ---------------- deterministic loss reduction ----------------
__global__ __launch_bounds__(256) void sum_part(
    const unsigned* __restrict__ d1m, const unsigned* __restrict__ d2m,
    float* __restrict__ ps)
{
  int bid = blockIdx.x, tid = threadIdx.x;
  const unsigned* src = (bid<64) ? (d1m + bid*1024) : (d2m + (size_t)(bid-64)*1024);
  float s = 0.f;
  for (int i=tid;i<1024;i+=256) s += __uint_as_float(src[i]);
  for (int off=32; off; off>>=1) s += __shfl_xor(s,off);
  __shared__ float red[4];
  if ((tid&63)==0) red[tid>>6]=s;
  __syncthreads();
  if (tid==0) ps[bid] = red[0]+red[1]+red[2]+red[3];
}

__global__ void loss_k(const float* __restrict__ ps, float* __restrict__ out){
  int tid = threadIdx.x;  // 128 threads
  float v = 0.f;
  if (tid < 64) v = ps[tid] * (1.0f/65536.0f);
  else if (tid < 96) v = ps[tid] * (1.0f/32768.0f);
  for (int off=32; off; off>>=1) v += __shfl_xor(v,off);
  __shared__ float red[2];
  if ((tid&63)==0) red[tid>>6]=v;
  __syncthreads();
  if (tid==0) out[0] = red[0]+red[1];
}

// ---------------- launch ----------------
extern "C" void kernel_launch(void* const* d_in, const int* in_sizes, int n_in,
                              void* d_out, int out_size, void* d_ws, size_t ws_size,
                              hipStream_t stream)
{
  (void)in_sizes; (void)n_in; (void)out_size;
  const float* in_pc = (const float*)d_in[0];
  const float* w1   = (const float*)d_in[1];
  const float* b1   = (const float*)d_in[2];
  const float* w2   = (const float*)d_in[3];
  const float* b2   = (const float*)d_in[4];
  const float* w3   = (const float*)d_in[5];
  const float* b3   = (const float*)d_in[6];
  const float* wenc = (const float*)d_in[7];
  const float* benc = (const float*)d_in[8];
  const float* wf1  = (const float*)d_in[9];
  const float* bfc1 = (const float*)d_in[10];
  const float* wf2  = (const float*)d_in[11];
  const float* bfc2 = (const float*)d_in[12];
  const float* wf3  = (const float*)d_in[13];
  const float* bfc3 = (const float*)d_in[14];
  const float* lng  = (const float*)d_in[15];
  const float* lnb  = (const float*)d_in[16];
  float* out = (float*)d_out;

  bool big = ws_size >= (size_t)(H2_BYTES + 2*1024*1024);
  char* ws = (char*)d_ws;
  unsigned short* h2b = (unsigned short*)ws;
  char* small = ws + (big ? H2_BYTES : 0);

  unsigned* gfeatU = (unsigned*)(small + OFF_GFEAT);
  float* pooled = (float*)(small + OFF_POOL);
  float* gcon = (float*)(small + OFF_GCON);
  float* emb  = (float*)(small + OFF_EMB);
  float* hd1  = (float*)(small + OFF_HD1);
  float* hd2  = (float*)(small + OFF_HD2);
  float* h3   = (float*)(small + OFF_H3);
  float* opc  = (float*)(small + OFF_OPC);
  unsigned* d1m = (unsigned*)(small + OFF_D1M);
  unsigned* d2m = (unsigned*)(small + OFF_D2M);
  float* ps   = (float*)(small + OFF_PS);
  unsigned short* w3b = (unsigned short*)(small + OFF_W3BF);

  hipMemsetAsync(small + OFF_GFEAT, 0, 8192 + 65536, stream);      // gfeat + pooled = 0
  hipMemsetAsync(small + OFF_D1M, 0x7F, 262144 + 131072, stream);  // d1m + d2m ~ +inf

  if (big){
    w3_cvt<<<512, 256, 0, stream>>>(w3, (unsigned*)w3b);
    conv12_full<<<dim3(256,4), 256, 0, stream>>>(in_pc, w1, b1, w2, b2, out, h2b, gfeatU);
    bcast_gcon<<<8196, 256, 0, stream>>>(gfeatU, out, w3, b3, gcon);
    conv3_pool<<<dim3(16,16), 512, 0, stream>>>(h2b, w3b, gcon, (unsigned*)pooled);
  } else {
    conv12_f32<<<dim3(256,4), 256, 0, stream>>>(in_pc, w1, b1, w2, b2, out, gfeatU);
    bcast_gcon<<<8196, 256, 0, stream>>>(gfeatU, out, w3, b3, gcon);
    conv3n<<<2048, 256, 0, stream>>>(out, gfeatU, w3, b3, (unsigned*)pooled);
  }
  fc_wave16<false><<<64,   256, 0, stream>>>(pooled, wenc, benc, emb, out + OUT_EMB, 1024, 256);
  fc_wave16<true ><<<128,  256, 0, stream>>>(emb, wf1, bfc1, hd1, nullptr, 256, 512);
  fc_wave16<true ><<<256,  256, 0, stream>>>(hd1, wf2, bfc2, hd2, nullptr, 512, 1024);
  fc_wave16<false><<<1536, 256, 0, stream>>>(hd2, wf3, bfc3, h3, nullptr, 1024, 6144);
  lnorm<<<16, 256, 0, stream>>>(h3, lng, lnb, opc, out + OUT_OPC);
  chamfer_all<<<4096, 256, 0, stream>>>(in_pc, opc, d1m, d2m);
  sum_part<<<96, 256, 0, stream>>>(d1m, d2m, ps);
  loss_k<<<1, 128, 0, stream>>>(ps, out + OUT_LOSS);
}

// Round 12
// 166.985 us; speedup vs baseline: 1.4230x; 1.1327x over previous
//
#include <hip/hip_runtime.h>

// output element offsets (f32 elements)
#define OUT_X0   0
#define OUT_EMB  16777216
#define OUT_OPC  16781312
#define OUT_LOSS 16879616

// small-buffer byte offsets (relative to `small` base)
#define OFF_GFEAT 0            // 8192     u32 float-bits [16][128]
#define OFF_POOL  8192         // 65536    u32 float-bits [16][1024]
#define OFF_GCON  73728        // 65536    f32 [16][1024]
#define OFF_EMB   139264       // 16384    f32 [16][256]
#define OFF_HD1   155648       // 32768    f32 [16][512]
#define OFF_HD2   188416       // 65536    f32 [16][1024]
#define OFF_H3    253952       // 393216   f32 [16][6144]
#define OFF_OPC   647168       // 393216   f32 [16][6144]
#define OFF_D1M   1040384      // 262144   u32 [16][4096]
#define OFF_D2M   1302528      // 131072   u32 [16][2048]
#define OFF_PS    1433600      // 384      f32 [96]
#define OFF_W3BF  1433984      // 524288   bf16 w3 [1024][256]
#define H2_BYTES  (16u*1024*1024)   // bf16 h2 [65536][128] at ws+0 (big path)

typedef short short8 __attribute__((ext_vector_type(8)));
typedef float f32x4  __attribute__((ext_vector_type(4)));

__device__ __forceinline__ unsigned short f2bf(float f){
  unsigned u = __float_as_uint(f);
  return (unsigned short)((u + 0x7FFFu + ((u >> 16) & 1u)) >> 16);
}

// ------- conv1+conv2 via MFMA: C[ch][pt]; x0 f32 + h2 bf16 + gfeat. -------
// blocks 0..511: conv (16 b x 32 pt-tiles of 128). blocks 512..1023: w3 cvt.
__global__ __launch_bounds__(256) void conv12_mfma(
    const float* __restrict__ in_pc,
    const float* __restrict__ w1, const float* __restrict__ b1,
    const float* __restrict__ w2, const float* __restrict__ b2,
    float* __restrict__ x0, unsigned short* __restrict__ h2b,
    unsigned* __restrict__ gfeatU,
    const float* __restrict__ w3, unsigned* __restrict__ w3bf)
{
  __shared__ unsigned short w2s[8192];   // [128 ch][64 c] bf16, XOR-swizzled
  __shared__ unsigned short h1s[8192];   // [128 pt][64 c] bf16, XOR-swizzled
  __shared__ float b2s[128];
  __shared__ unsigned gmax[128];
  int tid = threadIdx.x, bid = blockIdx.x;
  if (bid >= 512){   // folded w3 f32->bf16 pre-pass: 512*256 float2 = 131072
    int i = (bid-512)*256 + tid;
    float2 v = ((const float2*)w3)[i];
    w3bf[i] = (unsigned)f2bf(v.x) | ((unsigned)f2bf(v.y)<<16);
    return;
  }
  int b = bid >> 5;
  int nt0 = (bid & 31)*128;
  // stage w2 -> bf16 LDS (2048 float4)
  for (int i = tid; i < 2048; i += 256){
    int ch = i >> 4, q = i & 15;
    float4 v = ((const float4*)w2)[i];
    unsigned lo = (unsigned)f2bf(v.x) | ((unsigned)f2bf(v.y)<<16);
    unsigned hi = (unsigned)f2bf(v.z) | ((unsigned)f2bf(v.w)<<16);
    int byte = (ch*128 + q*8) ^ ((ch&7)<<4);
    *(uint2*)((char*)w2s + byte) = make_uint2(lo, hi);
  }
  if (tid < 128){ b2s[tid] = b2[tid]; gmax[tid] = 0u; }
  if (tid < 128){  // h1 for this block's 128 points
    int idx = b*4096 + nt0 + tid;
    const float* p = in_pc + (size_t)idx*3;
    float px=p[0], py=p[1], pz=p[2];
    unsigned hp[32];
    #pragma unroll
    for (int q=0;q<32;q++){
      int c = q*2;
      float v0 = fmaxf(fmaf(w1[c*3  ],px, fmaf(w1[c*3+1],py, fmaf(w1[c*3+2],pz, b1[c  ]))), 0.f);
      float v1 = fmaxf(fmaf(w1[c*3+3],px, fmaf(w1[c*3+4],py, fmaf(w1[c*3+5],pz, b1[c+1]))), 0.f);
      hp[q] = (unsigned)f2bf(v0) | ((unsigned)f2bf(v1)<<16);
    }
    #pragma unroll
    for (int q=0;q<8;q++){
      int byte = (tid*128 + q*16) ^ ((tid&7)<<4);
      *(uint4*)((char*)h1s + byte) = make_uint4(hp[q*4],hp[q*4+1],hp[q*4+2],hp[q*4+3]);
    }
  }
  __syncthreads();
  int lane = tid & 63, w = tid >> 6;
  int g = lane >> 4, p15 = lane & 15;
  f32x4 acc[8][2] = {};
  #pragma unroll
  for (int ks=0; ks<2; ks++){
    int kb = (ks*32 + g*8)*2;
    short8 bfr[2];
    #pragma unroll
    for (int nf=0;nf<2;nf++){
      int pt = w*32 + nf*16 + p15;
      bfr[nf] = *(const short8*)((const char*)h1s + ((pt*128 + kb) ^ ((pt&7)<<4)));
    }
    #pragma unroll
    for (int mf=0;mf<8;mf++){
      int ch = mf*16 + p15;
      short8 af = *(const short8*)((const char*)w2s + ((ch*128 + kb) ^ ((ch&7)<<4)));
      acc[mf][0] = __builtin_amdgcn_mfma_f32_16x16x32_bf16(af, bfr[0], acc[mf][0], 0,0,0);
      acc[mf][1] = __builtin_amdgcn_mfma_f32_16x16x32_bf16(af, bfr[1], acc[mf][1], 0,0,0);
    }
  }
  // epilogue: +bias, relu, x0 [ch][n] f32, h2 [n][ch] bf16, gfeat max
  int n_base = nt0 + w*32;
  #pragma unroll
  for (int mf=0; mf<8; mf++){
    int ch0 = mf*16 + g*4;
    float bias[4];
    #pragma unroll
    for (int j=0;j<4;j++) bias[j] = b2s[ch0+j];
    float vm[4] = {0.f,0.f,0.f,0.f};
    #pragma unroll
    for (int nf=0; nf<2; nf++){
      int n = n_base + nf*16 + p15;
      float v[4];
      #pragma unroll
      for (int j=0;j<4;j++){
        v[j] = fmaxf(acc[mf][nf][j] + bias[j], 0.f);
        vm[j] = fmaxf(vm[j], v[j]);
        x0[((size_t)(b*256 + ch0 + j))*4096 + n] = v[j];
      }
      unsigned lo = (unsigned)f2bf(v[0]) | ((unsigned)f2bf(v[1])<<16);
      unsigned hi = (unsigned)f2bf(v[2]) | ((unsigned)f2bf(v[3])<<16);
      *(uint2*)&h2b[((size_t)(b*4096 + n))*128 + ch0] = make_uint2(lo, hi);
    }
    #pragma unroll
    for (int j=0;j<4;j++){
      float m = vm[j];
      m = fmaxf(m, __shfl_xor(m,1));
      m = fmaxf(m, __shfl_xor(m,2));
      m = fmaxf(m, __shfl_xor(m,4));
      m = fmaxf(m, __shfl_xor(m,8));
      if (p15==0) atomicMax(&gmax[ch0+j], __float_as_uint(m));
    }
  }
  __syncthreads();
  if (tid < 128) atomicMax(&gfeatU[b*128 + tid], gmax[tid]);
}

// ---- gfeat bcast (8192 blocks) + gcon (4 blocks) ----
__global__ __launch_bounds__(256) void bcast_gcon(
    const unsigned* __restrict__ gfeatU, float* __restrict__ x0,
    const float* __restrict__ w3, const float* __restrict__ b3,
    float* __restrict__ gcon)
{
  __shared__ float gf[2048];
  int tid = threadIdx.x;
  if (blockIdx.x < 8192){
    unsigned U = blockIdx.x*256 + tid;
    int n4 = U & 1023, c = (U >> 10) & 127, b = U >> 17;
    float g = __uint_as_float(gfeatU[b*128+c]);
    float4 v = {g,g,g,g};
    ((float4*)x0)[(((size_t)b*256 + 128 + c)*4096)/4 + n4] = v;
  } else {
    for (int i=tid;i<2048;i+=256) gf[i] = __uint_as_float(gfeatU[i]);
    __syncthreads();
    int o = (blockIdx.x - 8192)*256 + tid;
    float bias = b3[o];
    float acc[16];
    #pragma unroll
    for (int b=0;b<16;b++) acc[b]=bias;
    for (int c=0;c<128;c++){
      float wv = w3[(size_t)o*256 + 128 + c];
      #pragma unroll
      for (int b=0;b<16;b++) acc[b] += gf[b*128+c]*wv;
    }
    #pragma unroll
    for (int b=0;b<16;b++) gcon[b*1024+o] = acc[b];
  }
}

// ------- conv3 MFMA GEMM (256n x 128k)x(128k -> 1024o) + relu + max-pool -------
__global__ __launch_bounds__(512) void conv3_pool(
    const unsigned short* __restrict__ h2b, const unsigned short* __restrict__ w3b,
    const float* __restrict__ gcon, unsigned* __restrict__ pooled)
{
  __shared__ unsigned short Al[256*128];
  __shared__ unsigned short Bl[256*128];
  int mt = blockIdx.x, b = blockIdx.y;
  int tid = threadIdx.x;
  {
    const uint4* src = (const uint4*)(h2b + ((size_t)b*4096 + mt*256)*128);
    #pragma unroll
    for (int i=0;i<8;i++){
      int idx = i*512 + tid;
      int r = idx>>4, kc = idx&15;
      uint4 v = src[(size_t)r*16 + kc];
      int byte = (r*256 + kc*16) ^ ((r&7)<<4);
      *(uint4*)((char*)Al + byte) = v;
    }
  }
  int lane = tid & 63, wid = tid >> 6;
  int wm = wid >> 2, wn = wid & 3;
  int mbase = wm*128, nbase = wn*64;
  for (int nt=0; nt<4; nt++){
    if (nt) __syncthreads();
    {
      #pragma unroll
      for (int i=0;i<8;i++){
        int idx = i*512 + tid;
        int c = idx>>4, kc = idx&15;
        uint4 v = *(const uint4*)(w3b + ((size_t)(nt*256+c)*256 + kc*8));
        int byte = (c*256 + kc*16) ^ ((c&7)<<4);
        *(uint4*)((char*)Bl + byte) = v;
      }
    }
    __syncthreads();
    f32x4 acc[8][4] = {};
    #pragma unroll
    for (int ks=0;ks<4;ks++){
      int kb = (ks*32 + (lane>>4)*8)*2;
      short8 af[8], bfr[4];
      #pragma unroll
      for (int mi=0;mi<8;mi++){
        int row = mbase + mi*16 + (lane&15);
        af[mi] = *(const short8*)((const char*)Al + ((row*256 + kb) ^ ((row&7)<<4)));
      }
      #pragma unroll
      for (int ni=0;ni<4;ni++){
        int col = nbase + ni*16 + (lane&15);
        bfr[ni] = *(const short8*)((const char*)Bl + ((col*256 + kb) ^ ((col&7)<<4)));
      }
      #pragma unroll
      for (int mi=0;mi<8;mi++){
        #pragma unroll
        for (int ni=0;ni<4;ni++)
          acc[mi][ni] = __builtin_amdgcn_mfma_f32_16x16x32_bf16(af[mi], bfr[ni], acc[mi][ni], 0,0,0);
      }
    }
    #pragma unroll
    for (int ni=0;ni<4;ni++){
      int o = nt*256 + nbase + ni*16 + (lane&15);
      float g = gcon[b*1024 + o];
      float m = 0.f;
      #pragma unroll
      for (int mi=0;mi<8;mi++){
        f32x4 a = acc[mi][ni];
        #pragma unroll
        for (int r=0;r<4;r++){ float v = a[r]+g; m = fmaxf(m, v); }
      }
      m = fmaxf(m, 0.f);
      m = fmaxf(m, __shfl_xor(m, 16));
      m = fmaxf(m, __shfl_xor(m, 32));
      if (lane < 16) atomicMax(&pooled[(size_t)b*1024+o], __float_as_uint(m));
    }
  }
}

// ---- fallback (small ws): conv12 writes x0 f32 directly + gfeat ----
__global__ __launch_bounds__(256) void conv12_f32(
    const float* __restrict__ in_pc,
    const float* __restrict__ w1, const float* __restrict__ b1,
    const float* __restrict__ w2, const float* __restrict__ b2,
    float* __restrict__ x0, unsigned* __restrict__ gfeatU)
{
  __shared__ unsigned gmax[32];
  int tid = threadIdx.x;
  if (tid < 32) gmax[tid] = 0u;
  __syncthreads();
  int idx = blockIdx.x*256 + tid;
  int b = idx >> 12, n = idx & 4095;
  int gy = blockIdx.y;
  int lane = tid & 63;
  const float* p = in_pc + (size_t)idx*3;
  float px=p[0], py=p[1], pz=p[2];
  float h1[64];
  #pragma unroll
  for (int c=0;c<64;c++)
    h1[c] = fmaxf(w1[c*3]*px + w1[c*3+1]*py + w1[c*3+2]*pz + b1[c], 0.f);
  #pragma unroll
  for (int j=0;j<32;j++){
    int o = gy*32 + j;
    float a = b2[o];
    #pragma unroll
    for (int c=0;c<64;c++) a += w2[o*64+c]*h1[c];
    a = fmaxf(a, 0.f);
    x0[((size_t)b*256 + o)*4096 + n] = a;
    float m = a;
    #pragma unroll
    for (int off=32; off; off>>=1) m = fmaxf(m, __shfl_xor(m, off));
    if (lane==0) atomicMax(&gmax[j], __float_as_uint(m));
  }
  __syncthreads();
  if (tid < 32) atomicMax(&gfeatU[b*128 + gy*32 + tid], gmax[tid]);
}

// ---- fallback conv3 ----
__global__ __launch_bounds__(256) void conv3n(
    const float* __restrict__ x0, const unsigned* __restrict__ gfeatU,
    const float* __restrict__ w3, const float* __restrict__ b3,
    unsigned* __restrict__ pooled)
{
  __shared__ float wrow[8][256];
  int b = blockIdx.x >> 7, og = (blockIdx.x & 127)*8, tid = threadIdx.x;
  for (int i=tid;i<2048;i+=256){ int j=i>>8, c=i&255; wrow[j][c]=w3[(size_t)(og+j)*256+c]; }
  __syncthreads();
  float gconst[8];
  #pragma unroll
  for (int j=0;j<8;j++){
    float g = b3[og+j];
    for (int c=0;c<128;c++) g += __uint_as_float(gfeatU[b*128+c])*wrow[j][128+c];
    gconst[j] = g;
  }
  const float* xb = x0 + (size_t)b*256*4096;
  float m[8];
  #pragma unroll
  for (int j=0;j<8;j++) m[j]=0.f;
  for (int n=tid;n<4096;n+=256){
    float v[8];
    #pragma unroll
    for (int j=0;j<8;j++) v[j]=gconst[j];
    for (int c=0;c<128;c++){
      float xv = xb[(size_t)c*4096 + n];
      #pragma unroll
      for (int j=0;j<8;j++) v[j] += xv*wrow[j][c];
    }
    #pragma unroll
    for (int j=0;j<8;j++) m[j] = fmaxf(m[j], v[j]);
  }
  #pragma unroll
  for (int j=0;j<8;j++){
    float v = m[j];
    for (int off=32; off; off>>=1) v = fmaxf(v, __shfl_xor(v, off));
    if ((tid&63)==0) atomicMax(&pooled[(size_t)b*1024+og+j], __float_as_uint(v));
  }
}

// ------- fc: one wave per output o, all 16 batches in registers -------
template<bool RELU>
__global__ __launch_bounds__(256) void fc_wave16(
    const float* __restrict__ A, const float* __restrict__ W,
    const float* __restrict__ bias, float* __restrict__ out,
    float* __restrict__ out2, int K, int O)
{
  int lane = threadIdx.x & 63, w = threadIdx.x >> 6;
  int o = blockIdx.x*4 + w;
  const float* Wr = W + (size_t)o*K;
  float acc[16];
  #pragma unroll
  for (int b=0;b<16;b++) acc[b]=0.f;
  for (int k = lane*4; k < K; k += 256){
    float4 wv = *(const float4*)&Wr[k];
    #pragma unroll
    for (int b=0;b<16;b++){
      float4 av = *(const float4*)&A[(size_t)b*K + k];
      acc[b] += wv.x*av.x + wv.y*av.y + wv.z*av.z + wv.w*av.w;
    }
  }
  #pragma unroll
  for (int b=0;b<16;b++){
    float v = acc[b];
    #pragma unroll
    for (int off=32; off; off>>=1) v += __shfl_xor(v, off);
    if (lane==0){
      v += bias[o];
      if (RELU) v = fmaxf(v, 0.f);
      out[(size_t)b*O+o] = v;
      if (out2) out2[(size_t)b*O+o] = v;
    }
  }
}

// ---------------- LayerNorm over 6144 per batch row ----------------
__global__ __launch_bounds__(256) void lnorm(
    const float* __restrict__ h3, const float* __restrict__ g,
    const float* __restrict__ be, float* __restrict__ outf,
    float* __restrict__ outb)
{
  int b = blockIdx.x, tid = threadIdx.x;
  const float* x = h3 + b*6144;
  float s=0.f, s2=0.f;
  for (int i=tid;i<6144;i+=256){ float v=x[i]; s+=v; s2+=v*v; }
  for (int off=32; off; off>>=1){ s += __shfl_xor(s,off); s2 += __shfl_xor(s2,off); }
  __shared__ float red[8];
  int lane = tid&63, wid = tid>>6;
  if (lane==0){ red[wid]=s; red[4+wid]=s2; }
  __syncthreads();
  s  = red[0]+red[1]+red[2]+red[3];
  s2 = red[4]+red[5]+red[6]+red[7];
  float mu  = s * (1.f/6144.f);
  float var = s2 * (1.f/6144.f) - mu*mu;
  float inv = rsqrtf(var + 1e-5f);
  for (int i=tid;i<6144;i+=256){
    float v = (x[i]-mu)*inv*g[i] + be[i];
    outf[b*6144+i] = v;
    outb[b*6144+i] = v;
  }
}

// ---- chamfer: 1 query/thread, q^2-2pq decomposition ----
__global__ __launch_bounds__(256) void chamfer_all(
    const float* __restrict__ in_pc, const float* __restrict__ opc,
    unsigned* __restrict__ d1m, unsigned* __restrict__ d2m)
{
  __shared__ float sx[256], sy[256], sz[256], s2[256];
  int bid = blockIdx.x, tid = threadIdx.x;
  const float* stage;
  const float* qry;
  unsigned* outp;
  if (bid < 2048){
    int xt = bid & 15, b = (bid >> 4) & 15, mt = bid >> 8;
    stage = opc + b*6144 + mt*768;
    qry   = in_pc + ((size_t)b*4096 + xt*256 + tid)*3;
    outp  = d1m + b*4096 + xt*256 + tid;
  } else {
    int r = bid - 2048;
    int xt = r & 7, b = (r >> 3) & 15, nt = r >> 7;
    stage = in_pc + ((size_t)b*4096 + nt*256)*3;
    qry   = opc + b*6144 + (xt*256 + tid)*3;
    outp  = d2m + b*2048 + xt*256 + tid;
  }
  {
    const float* S = stage + tid*3;
    float x=S[0], y=S[1], z=S[2];
    sx[tid]=x; sy[tid]=y; sz[tid]=z; s2[tid]=x*x+y*y+z*z;
  }
  __syncthreads();
  float qx=qry[0], qy=qry[1], qz=qry[2];
  float p2 = qx*qx + qy*qy + qz*qz;
  float ma=3.0e38f, mb=3.0e38f;
  #pragma unroll 2
  for (int i=0;i<64;i++){
    float4 X  = *(const float4*)&sx[i*4];
    float4 Y  = *(const float4*)&sy[i*4];
    float4 Z  = *(const float4*)&sz[i*4];
    float4 Q2 = *(const float4*)&s2[i*4];
    float t;
    t = fmaf(-2.f, fmaf(qx,X.x,fmaf(qy,Y.x,qz*Z.x)), Q2.x); ma = fminf(ma,t);
    t = fmaf(-2.f, fmaf(qx,X.y,fmaf(qy,Y.y,qz*Z.y)), Q2.y); mb = fminf(mb,t);
    t = fmaf(-2.f, fmaf(qx,X.z,fmaf(qy,Y.z,qz*Z.z)), Q2.z); ma = fminf(ma,t);
    t = fmaf(-2.f, fmaf(qx,X.w,fmaf(qy,Y.w,qz*Z.w)), Q2.w); mb = fminf(mb,t);
  }
  float d = fmaxf(p2 + fminf(ma, mb), 0.f);
  atomicMin(outp, __float_as_uint(d));
}

// ---------------- deterministic loss reduction ----------------
__global__ __launch_bounds__(256) void sum_part(
    const unsigned* __restrict__ d1m, const unsigned* __restrict__ d2m,
    float* __restrict__ ps)
{
  int bid = blockIdx.x, tid = threadIdx.x;
  const unsigned* src = (bid<64) ? (d1m + bid*1024) : (d2m + (size_t)(bid-64)*1024);
  float s = 0.f;
  for (int i=tid;i<1024;i+=256) s += __uint_as_float(src[i]);
  for (int off=32; off; off>>=1) s += __shfl_xor(s,off);
  __shared__ float red[4];
  if ((tid&63)==0) red[tid>>6]=s;
  __syncthreads();
  if (tid==0) ps[bid] = red[0]+red[1]+red[2]+red[3];
}

__global__ void loss_k(const float* __restrict__ ps, float* __restrict__ out){
  int tid = threadIdx.x;  // 128 threads
  float v = 0.f;
  if (tid < 64) v = ps[tid] * (1.0f/65536.0f);
  else if (tid < 96) v = ps[tid] * (1.0f/32768.0f);
  for (int off=32; off; off>>=1) v += __shfl_xor(v,off);
  __shared__ float red[2];
  if ((tid&63)==0) red[tid>>6]=v;
  __syncthreads();
  if (tid==0) out[0] = red[0]+red[1];
}

// ---------------- launch ----------------
extern "C" void kernel_launch(void* const* d_in, const int* in_sizes, int n_in,
                              void* d_out, int out_size, void* d_ws, size_t ws_size,
                              hipStream_t stream)
{
  (void)in_sizes; (void)n_in; (void)out_size;
  const float* in_pc = (const float*)d_in[0];
  const float* w1   = (const float*)d_in[1];
  const float* b1   = (const float*)d_in[2];
  const float* w2   = (const float*)d_in[3];
  const float* b2   = (const float*)d_in[4];
  const float* w3   = (const float*)d_in[5];
  const float* b3   = (const float*)d_in[6];
  const float* wenc = (const float*)d_in[7];
  const float* benc = (const float*)d_in[8];
  const float* wf1  = (const float*)d_in[9];
  const float* bfc1 = (const float*)d_in[10];
  const float* wf2  = (const float*)d_in[11];
  const float* bfc2 = (const float*)d_in[12];
  const float* wf3  = (const float*)d_in[13];
  const float* bfc3 = (const float*)d_in[14];
  const float* lng  = (const float*)d_in[15];
  const float* lnb  = (const float*)d_in[16];
  float* out = (float*)d_out;

  bool big = ws_size >= (size_t)(H2_BYTES + 2*1024*1024);
  char* ws = (char*)d_ws;
  unsigned short* h2b = (unsigned short*)ws;
  char* small = ws + (big ? H2_BYTES : 0);

  unsigned* gfeatU = (unsigned*)(small + OFF_GFEAT);
  float* pooled = (float*)(small + OFF_POOL);
  float* gcon = (float*)(small + OFF_GCON);
  float* emb  = (float*)(small + OFF_EMB);
  float* hd1  = (float*)(small + OFF_HD1);
  float* hd2  = (float*)(small + OFF_HD2);
  float* h3   = (float*)(small + OFF_H3);
  float* opc  = (float*)(small + OFF_OPC);
  unsigned* d1m = (unsigned*)(small + OFF_D1M);
  unsigned* d2m = (unsigned*)(small + OFF_D2M);
  float* ps   = (float*)(small + OFF_PS);
  unsigned short* w3b = (unsigned short*)(small + OFF_W3BF);

  hipMemsetAsync(small + OFF_GFEAT, 0, 8192 + 65536, stream);      // gfeat + pooled = 0
  hipMemsetAsync(small + OFF_D1M, 0x7F, 262144 + 131072, stream);  // d1m + d2m ~ +inf

  if (big){
    conv12_mfma<<<1024, 256, 0, stream>>>(in_pc, w1, b1, w2, b2, out, h2b, gfeatU,
                                          w3, (unsigned*)w3b);
    bcast_gcon<<<8196, 256, 0, stream>>>(gfeatU, out, w3, b3, gcon);
    conv3_pool<<<dim3(16,16), 512, 0, stream>>>(h2b, w3b, gcon, (unsigned*)pooled);
  } else {
    conv12_f32<<<dim3(256,4), 256, 0, stream>>>(in_pc, w1, b1, w2, b2, out, gfeatU);
    bcast_gcon<<<8196, 256, 0, stream>>>(gfeatU, out, w3, b3, gcon);
    conv3n<<<2048, 256, 0, stream>>>(out, gfeatU, w3, b3, (unsigned*)pooled);
  }
  fc_wave16<false><<<64,   256, 0, stream>>>(pooled, wenc, benc, emb, out + OUT_EMB, 1024, 256);
  fc_wave16<true ><<<128,  256, 0, stream>>>(emb, wf1, bfc1, hd1, nullptr, 256, 512);
  fc_wave16<true ><<<256,  256, 0, stream>>>(hd1, wf2, bfc2, hd2, nullptr, 512, 1024);
  fc_wave16<false><<<1536, 256, 0, stream>>>(hd2, wf3, bfc3, h3, nullptr, 1024, 6144);
  lnorm<<<16, 256, 0, stream>>>(h3, lng, lnb, opc, out + OUT_OPC);
  chamfer_all<<<4096, 256, 0, stream>>>(in_pc, opc, d1m, d2m);
  sum_part<<<96, 256, 0, stream>>>(d1m, d2m, ps);
  loss_k<<<1, 128, 0, stream>>>(ps, out + OUT_LOSS);
}

// Round 13
// 166.140 us; speedup vs baseline: 1.4302x; 1.0051x over previous
//
#include <hip/hip_runtime.h>

// output element offsets (f32 elements)
#define OUT_X0   0
#define OUT_EMB  16777216
#define OUT_OPC  16781312
#define OUT_LOSS 16879616

// small-buffer byte offsets (relative to `small` base)
#define OFF_GFEAT 0            // 8192     u32 float-bits [16][128]
#define OFF_POOL  8192         // 65536    u32 float-bits [16][1024]
#define OFF_GCON  73728        // 65536    f32 [16][1024]
#define OFF_EMB   139264       // 16384    f32 [16][256]
#define OFF_HD1   155648       // 32768    f32 [16][512]
#define OFF_HD2   188416       // 65536    f32 [16][1024]
#define OFF_H3    253952       // 393216   f32 [16][6144]
#define OFF_OPC   647168       // 393216   f32 [16][6144]
#define OFF_D1M   1040384      // 262144   u32 [16][4096]
#define OFF_D2M   1302528      // 131072   u32 [16][2048]
#define OFF_PS    1433600      // 384      f32 [96]
#define OFF_W3BF  1433984      // 524288   bf16 w3 [1024][256]
#define OFF_CNT   1958272      // 4        int counter
#define H2_BYTES  (16u*1024*1024)   // bf16 h2 [65536][128] at ws+0 (big path)

typedef short short8 __attribute__((ext_vector_type(8)));
typedef float f32x4  __attribute__((ext_vector_type(4)));

__device__ __forceinline__ unsigned short f2bf(float f){
  unsigned u = __float_as_uint(f);
  return (unsigned short)((u + 0x7FFFu + ((u >> 16) & 1u)) >> 16);
}

// ------- conv1+conv2 via MFMA: C[ch][pt]; x0 f32 + h2 bf16 + gfeat. -------
// blocks 0..511: conv (16 b x 32 pt-tiles of 128). blocks 512..1023: w3 cvt.
__global__ __launch_bounds__(256) void conv12_mfma(
    const float* __restrict__ in_pc,
    const float* __restrict__ w1, const float* __restrict__ b1,
    const float* __restrict__ w2, const float* __restrict__ b2,
    float* __restrict__ x0, unsigned short* __restrict__ h2b,
    unsigned* __restrict__ gfeatU,
    const float* __restrict__ w3, unsigned* __restrict__ w3bf)
{
  __shared__ unsigned short w2s[8192];   // [128 ch][64 c] bf16, XOR-swizzled
  __shared__ unsigned short h1s[8192];   // [128 pt][64 c] bf16, XOR-swizzled
  __shared__ float b2s[128];
  __shared__ unsigned gmax[128];
  int tid = threadIdx.x, bid = blockIdx.x;
  if (bid >= 512){   // folded w3 f32->bf16 pre-pass: 512*256 float2 = 131072
    int i = (bid-512)*256 + tid;
    float2 v = ((const float2*)w3)[i];
    w3bf[i] = (unsigned)f2bf(v.x) | ((unsigned)f2bf(v.y)<<16);
    return;
  }
  int b = bid >> 5;
  int nt0 = (bid & 31)*128;
  // stage w2 -> bf16 LDS (2048 float4)
  for (int i = tid; i < 2048; i += 256){
    int ch = i >> 4, q = i & 15;
    float4 v = ((const float4*)w2)[i];
    unsigned lo = (unsigned)f2bf(v.x) | ((unsigned)f2bf(v.y)<<16);
    unsigned hi = (unsigned)f2bf(v.z) | ((unsigned)f2bf(v.w)<<16);
    int byte = (ch*128 + q*8) ^ ((ch&7)<<4);
    *(uint2*)((char*)w2s + byte) = make_uint2(lo, hi);
  }
  if (tid < 128){ b2s[tid] = b2[tid]; gmax[tid] = 0u; }
  { // h1: 2 threads per point, 32 channels each
    int pt = tid & 127;
    int qb = (tid >> 7) * 16;       // channel-pair base: 0 or 16
    int idx = b*4096 + nt0 + pt;
    const float* p = in_pc + (size_t)idx*3;
    float px=p[0], py=p[1], pz=p[2];
    unsigned hp[16];
    #pragma unroll
    for (int q=0;q<16;q++){
      int c = (qb + q)*2;
      float v0 = fmaxf(fmaf(w1[c*3  ],px, fmaf(w1[c*3+1],py, fmaf(w1[c*3+2],pz, b1[c  ]))), 0.f);
      float v1 = fmaxf(fmaf(w1[c*3+3],px, fmaf(w1[c*3+4],py, fmaf(w1[c*3+5],pz, b1[c+1]))), 0.f);
      hp[q] = (unsigned)f2bf(v0) | ((unsigned)f2bf(v1)<<16);
    }
    #pragma unroll
    for (int t=0;t<4;t++){
      int byte = (pt*128 + qb*4 + t*16) ^ ((pt&7)<<4);
      *(uint4*)((char*)h1s + byte) = make_uint4(hp[t*4],hp[t*4+1],hp[t*4+2],hp[t*4+3]);
    }
  }
  __syncthreads();
  int lane = tid & 63, w = tid >> 6;
  int g = lane >> 4, p15 = lane & 15;
  f32x4 acc[8][2] = {};
  #pragma unroll
  for (int ks=0; ks<2; ks++){
    int kb = (ks*32 + g*8)*2;
    short8 bfr[2];
    #pragma unroll
    for (int nf=0;nf<2;nf++){
      int pt = w*32 + nf*16 + p15;
      bfr[nf] = *(const short8*)((const char*)h1s + ((pt*128 + kb) ^ ((pt&7)<<4)));
    }
    #pragma unroll
    for (int mf=0;mf<8;mf++){
      int ch = mf*16 + p15;
      short8 af = *(const short8*)((const char*)w2s + ((ch*128 + kb) ^ ((ch&7)<<4)));
      acc[mf][0] = __builtin_amdgcn_mfma_f32_16x16x32_bf16(af, bfr[0], acc[mf][0], 0,0,0);
      acc[mf][1] = __builtin_amdgcn_mfma_f32_16x16x32_bf16(af, bfr[1], acc[mf][1], 0,0,0);
    }
  }
  // epilogue: +bias, relu, x0 [ch][n] f32, h2 [n][ch] bf16, gfeat max
  int n_base = nt0 + w*32;
  #pragma unroll
  for (int mf=0; mf<8; mf++){
    int ch0 = mf*16 + g*4;
    float bias[4];
    #pragma unroll
    for (int j=0;j<4;j++) bias[j] = b2s[ch0+j];
    float vm[4] = {0.f,0.f,0.f,0.f};
    #pragma unroll
    for (int nf=0; nf<2; nf++){
      int n = n_base + nf*16 + p15;
      float v[4];
      #pragma unroll
      for (int j=0;j<4;j++){
        v[j] = fmaxf(acc[mf][nf][j] + bias[j], 0.f);
        vm[j] = fmaxf(vm[j], v[j]);
        x0[((size_t)(b*256 + ch0 + j))*4096 + n] = v[j];
      }
      unsigned lo = (unsigned)f2bf(v[0]) | ((unsigned)f2bf(v[1])<<16);
      unsigned hi = (unsigned)f2bf(v[2]) | ((unsigned)f2bf(v[3])<<16);
      *(uint2*)&h2b[((size_t)(b*4096 + n))*128 + ch0] = make_uint2(lo, hi);
    }
    #pragma unroll
    for (int j=0;j<4;j++){
      float m = vm[j];
      m = fmaxf(m, __shfl_xor(m,1));
      m = fmaxf(m, __shfl_xor(m,2));
      m = fmaxf(m, __shfl_xor(m,4));
      m = fmaxf(m, __shfl_xor(m,8));
      if (p15==0) atomicMax(&gmax[ch0+j], __float_as_uint(m));
    }
  }
  __syncthreads();
  if (tid < 128) atomicMax(&gfeatU[b*128 + tid], gmax[tid]);
}

// ---- gfeat bcast (8192 blocks) + gcon (4 blocks) ----
__global__ __launch_bounds__(256) void bcast_gcon(
    const unsigned* __restrict__ gfeatU, float* __restrict__ x0,
    const float* __restrict__ w3, const float* __restrict__ b3,
    float* __restrict__ gcon)
{
  __shared__ float gf[2048];
  int tid = threadIdx.x;
  if (blockIdx.x < 8192){
    unsigned U = blockIdx.x*256 + tid;
    int n4 = U & 1023, c = (U >> 10) & 127, b = U >> 17;
    float g = __uint_as_float(gfeatU[b*128+c]);
    float4 v = {g,g,g,g};
    ((float4*)x0)[(((size_t)b*256 + 128 + c)*4096)/4 + n4] = v;
  } else {
    for (int i=tid;i<2048;i+=256) gf[i] = __uint_as_float(gfeatU[i]);
    __syncthreads();
    int o = (blockIdx.x - 8192)*256 + tid;
    float bias = b3[o];
    float acc[16];
    #pragma unroll
    for (int b=0;b<16;b++) acc[b]=bias;
    for (int c=0;c<128;c++){
      float wv = w3[(size_t)o*256 + 128 + c];
      #pragma unroll
      for (int b=0;b<16;b++) acc[b] += gf[b*128+c]*wv;
    }
    #pragma unroll
    for (int b=0;b<16;b++) gcon[b*1024+o] = acc[b];
  }
}

// ------- conv3 MFMA GEMM: 128m tile, 8x128o steps; 64KB LDS -> 2 blocks/CU -------
__global__ __launch_bounds__(512) void conv3_pool(
    const unsigned short* __restrict__ h2b, const unsigned short* __restrict__ w3b,
    const float* __restrict__ gcon, unsigned* __restrict__ pooled)
{
  __shared__ unsigned short Al[128*128];
  __shared__ unsigned short Bl[128*128];
  int mt = blockIdx.x, b = blockIdx.y;   // mt < 32
  int tid = threadIdx.x;
  { // stage A: 128 rows x 128 k
    const uint4* src = (const uint4*)(h2b + ((size_t)b*4096 + mt*128)*128);
    #pragma unroll
    for (int i=0;i<4;i++){
      int idx = i*512 + tid;
      int r = idx>>4, kc = idx&15;
      uint4 v = src[idx];
      int byte = (r*256 + kc*16) ^ ((r&7)<<4);
      *(uint4*)((char*)Al + byte) = v;
    }
  }
  int lane = tid & 63, wid = tid >> 6;
  int wm = wid >> 2, wn = wid & 3;       // 2x4 waves over 128m x 128o
  int mbase = wm*64, nbase = wn*32;
  for (int nt=0; nt<8; nt++){
    if (nt) __syncthreads();
    { // stage B: 128 cols x 128 k
      #pragma unroll
      for (int i=0;i<4;i++){
        int idx = i*512 + tid;
        int c = idx>>4, kc = idx&15;
        uint4 v = *(const uint4*)(w3b + ((size_t)(nt*128+c)*256 + kc*8));
        int byte = (c*256 + kc*16) ^ ((c&7)<<4);
        *(uint4*)((char*)Bl + byte) = v;
      }
    }
    __syncthreads();
    f32x4 acc[4][2] = {};
    #pragma unroll
    for (int ks=0;ks<4;ks++){
      int kb = (ks*32 + (lane>>4)*8)*2;
      short8 af[4], bfr[2];
      #pragma unroll
      for (int mi=0;mi<4;mi++){
        int row = mbase + mi*16 + (lane&15);
        af[mi] = *(const short8*)((const char*)Al + ((row*256 + kb) ^ ((row&7)<<4)));
      }
      #pragma unroll
      for (int ni=0;ni<2;ni++){
        int col = nbase + ni*16 + (lane&15);
        bfr[ni] = *(const short8*)((const char*)Bl + ((col*256 + kb) ^ ((col&7)<<4)));
      }
      #pragma unroll
      for (int mi=0;mi<4;mi++){
        #pragma unroll
        for (int ni=0;ni<2;ni++)
          acc[mi][ni] = __builtin_amdgcn_mfma_f32_16x16x32_bf16(af[mi], bfr[ni], acc[mi][ni], 0,0,0);
      }
    }
    #pragma unroll
    for (int ni=0;ni<2;ni++){
      int o = nt*128 + nbase + ni*16 + (lane&15);
      float g = gcon[b*1024 + o];
      float m = 0.f;
      #pragma unroll
      for (int mi=0;mi<4;mi++){
        f32x4 a = acc[mi][ni];
        #pragma unroll
        for (int r=0;r<4;r++){ float v = a[r]+g; m = fmaxf(m, v); }
      }
      m = fmaxf(m, 0.f);
      m = fmaxf(m, __shfl_xor(m, 16));
      m = fmaxf(m, __shfl_xor(m, 32));
      if (lane < 16) atomicMax(&pooled[(size_t)b*1024+o], __float_as_uint(m));
    }
  }
}

// ---- fallback (small ws): conv12 writes x0 f32 directly + gfeat ----
__global__ __launch_bounds__(256) void conv12_f32(
    const float* __restrict__ in_pc,
    const float* __restrict__ w1, const float* __restrict__ b1,
    const float* __restrict__ w2, const float* __restrict__ b2,
    float* __restrict__ x0, unsigned* __restrict__ gfeatU)
{
  __shared__ unsigned gmax[32];
  int tid = threadIdx.x;
  if (tid < 32) gmax[tid] = 0u;
  __syncthreads();
  int idx = blockIdx.x*256 + tid;
  int b = idx >> 12, n = idx & 4095;
  int gy = blockIdx.y;
  int lane = tid & 63;
  const float* p = in_pc + (size_t)idx*3;
  float px=p[0], py=p[1], pz=p[2];
  float h1[64];
  #pragma unroll
  for (int c=0;c<64;c++)
    h1[c] = fmaxf(w1[c*3]*px + w1[c*3+1]*py + w1[c*3+2]*pz + b1[c], 0.f);
  #pragma unroll
  for (int j=0;j<32;j++){
    int o = gy*32 + j;
    float a = b2[o];
    #pragma unroll
    for (int c=0;c<64;c++) a += w2[o*64+c]*h1[c];
    a = fmaxf(a, 0.f);
    x0[((size_t)b*256 + o)*4096 + n] = a;
    float m = a;
    #pragma unroll
    for (int off=32; off; off>>=1) m = fmaxf(m, __shfl_xor(m, off));
    if (lane==0) atomicMax(&gmax[j], __float_as_uint(m));
  }
  __syncthreads();
  if (tid < 32) atomicMax(&gfeatU[b*128 + gy*32 + tid], gmax[tid]);
}

// ---- fallback conv3 ----
__global__ __launch_bounds__(256) void conv3n(
    const float* __restrict__ x0, const unsigned* __restrict__ gfeatU,
    const float* __restrict__ w3, const float* __restrict__ b3,
    unsigned* __restrict__ pooled)
{
  __shared__ float wrow[8][256];
  int b = blockIdx.x >> 7, og = (blockIdx.x & 127)*8, tid = threadIdx.x;
  for (int i=tid;i<2048;i+=256){ int j=i>>8, c=i&255; wrow[j][c]=w3[(size_t)(og+j)*256+c]; }
  __syncthreads();
  float gconst[8];
  #pragma unroll
  for (int j=0;j<8;j++){
    float g = b3[og+j];
    for (int c=0;c<128;c++) g += __uint_as_float(gfeatU[b*128+c])*wrow[j][128+c];
    gconst[j] = g;
  }
  const float* xb = x0 + (size_t)b*256*4096;
  float m[8];
  #pragma unroll
  for (int j=0;j<8;j++) m[j]=0.f;
  for (int n=tid;n<4096;n+=256){
    float v[8];
    #pragma unroll
    for (int j=0;j<8;j++) v[j]=gconst[j];
    for (int c=0;c<128;c++){
      float xv = xb[(size_t)c*4096 + n];
      #pragma unroll
      for (int j=0;j<8;j++) v[j] += xv*wrow[j][c];
    }
    #pragma unroll
    for (int j=0;j<8;j++) m[j] = fmaxf(m[j], v[j]);
  }
  #pragma unroll
  for (int j=0;j<8;j++){
    float v = m[j];
    for (int off=32; off; off>>=1) v = fmaxf(v, __shfl_xor(v, off));
    if ((tid&63)==0) atomicMax(&pooled[(size_t)b*1024+og+j], __float_as_uint(v));
  }
}

// ------- fc: one wave per output o, all 16 batches in registers -------
template<bool RELU>
__global__ __launch_bounds__(256) void fc_wave16(
    const float* __restrict__ A, const float* __restrict__ W,
    const float* __restrict__ bias, float* __restrict__ out,
    float* __restrict__ out2, int K, int O)
{
  int lane = threadIdx.x & 63, w = threadIdx.x >> 6;
  int o = blockIdx.x*4 + w;
  const float* Wr = W + (size_t)o*K;
  float acc[16];
  #pragma unroll
  for (int b=0;b<16;b++) acc[b]=0.f;
  for (int k = lane*4; k < K; k += 256){
    float4 wv = *(const float4*)&Wr[k];
    #pragma unroll
    for (int b=0;b<16;b++){
      float4 av = *(const float4*)&A[(size_t)b*K + k];
      acc[b] += wv.x*av.x + wv.y*av.y + wv.z*av.z + wv.w*av.w;
    }
  }
  #pragma unroll
  for (int b=0;b<16;b++){
    float v = acc[b];
    #pragma unroll
    for (int off=32; off; off>>=1) v += __shfl_xor(v, off);
    if (lane==0){
      v += bias[o];
      if (RELU) v = fmaxf(v, 0.f);
      out[(size_t)b*O+o] = v;
      if (out2) out2[(size_t)b*O+o] = v;
    }
  }
}

// ---------------- LayerNorm (also zeroes the sum counter) ----------------
__global__ __launch_bounds__(256) void lnorm(
    const float* __restrict__ h3, const float* __restrict__ g,
    const float* __restrict__ be, float* __restrict__ outf,
    float* __restrict__ outb, int* __restrict__ cnt)
{
  int b = blockIdx.x, tid = threadIdx.x;
  if (b==0 && tid==0) *cnt = 0;
  const float* x = h3 + b*6144;
  float s=0.f, s2=0.f;
  for (int i=tid;i<6144;i+=256){ float v=x[i]; s+=v; s2+=v*v; }
  for (int off=32; off; off>>=1){ s += __shfl_xor(s,off); s2 += __shfl_xor(s2,off); }
  __shared__ float red[8];
  int lane = tid&63, wid = tid>>6;
  if (lane==0){ red[wid]=s; red[4+wid]=s2; }
  __syncthreads();
  s  = red[0]+red[1]+red[2]+red[3];
  s2 = red[4]+red[5]+red[6]+red[7];
  float mu  = s * (1.f/6144.f);
  float var = s2 * (1.f/6144.f) - mu*mu;
  float inv = rsqrtf(var + 1e-5f);
  for (int i=tid;i<6144;i+=256){
    float v = (x[i]-mu)*inv*g[i] + be[i];
    outf[b*6144+i] = v;
    outb[b*6144+i] = v;
  }
}

// ---- chamfer: stage (-2x,-2y,-2z,q^2); 3 FMA + 1 min per pair ----
__global__ __launch_bounds__(256) void chamfer_all(
    const float* __restrict__ in_pc, const float* __restrict__ opc,
    unsigned* __restrict__ d1m, unsigned* __restrict__ d2m)
{
  __shared__ float sX[256], sY[256], sZ[256], sQ[256];
  int bid = blockIdx.x, tid = threadIdx.x;
  const float* stage;
  const float* qry;
  unsigned* outp;
  if (bid < 2048){
    int xt = bid & 15, b = (bid >> 4) & 15, mt = bid >> 8;
    stage = opc + b*6144 + mt*768;
    qry   = in_pc + ((size_t)b*4096 + xt*256 + tid)*3;
    outp  = d1m + b*4096 + xt*256 + tid;
  } else {
    int r = bid - 2048;
    int xt = r & 7, b = (r >> 3) & 15, nt = r >> 7;
    stage = in_pc + ((size_t)b*4096 + nt*256)*3;
    qry   = opc + b*6144 + (xt*256 + tid)*3;
    outp  = d2m + b*2048 + xt*256 + tid;
  }
  {
    const float* S = stage + tid*3;
    float x=S[0], y=S[1], z=S[2];
    sX[tid]=-2.f*x; sY[tid]=-2.f*y; sZ[tid]=-2.f*z; sQ[tid]=x*x+y*y+z*z;
  }
  __syncthreads();
  float qx=qry[0], qy=qry[1], qz=qry[2];
  float p2 = qx*qx + qy*qy + qz*qz;
  float ma=3.0e38f, mb=3.0e38f, mc=3.0e38f, md=3.0e38f;
  #pragma unroll 4
  for (int i=0;i<64;i++){
    float4 X = *(const float4*)&sX[i*4];
    float4 Y = *(const float4*)&sY[i*4];
    float4 Z = *(const float4*)&sZ[i*4];
    float4 Q = *(const float4*)&sQ[i*4];
    float t;
    t = fmaf(qx,X.x, fmaf(qy,Y.x, fmaf(qz,Z.x, Q.x))); ma = fminf(ma,t);
    t = fmaf(qx,X.y, fmaf(qy,Y.y, fmaf(qz,Z.y, Q.y))); mb = fminf(mb,t);
    t = fmaf(qx,X.z, fmaf(qy,Y.z, fmaf(qz,Z.z, Q.z))); mc = fminf(mc,t);
    t = fmaf(qx,X.w, fmaf(qy,Y.w, fmaf(qz,Z.w, Q.w))); md = fminf(md,t);
  }
  float d = fmaxf(p2 + fminf(fminf(ma,mb), fminf(mc,md)), 0.f);
  atomicMin(outp, __float_as_uint(d));
}

// ---- fused deterministic loss reduction (96 partials + last-block finish) ----
__global__ __launch_bounds__(256) void sum_loss(
    const unsigned* __restrict__ d1m, const unsigned* __restrict__ d2m,
    float* __restrict__ ps, int* __restrict__ cnt, float* __restrict__ out)
{
  int bid = blockIdx.x, tid = threadIdx.x;
  __shared__ float red[4];
  __shared__ int last;
  {
    const unsigned* src = (bid<64) ? (d1m + bid*1024) : (d2m + (size_t)(bid-64)*1024);
    float s = 0.f;
    for (int i=tid;i<1024;i+=256) s += __uint_as_float(src[i]);
    for (int off=32; off; off>>=1) s += __shfl_xor(s,off);
    if ((tid&63)==0) red[tid>>6]=s;
    __syncthreads();
    if (tid==0){
      ps[bid] = red[0]+red[1]+red[2]+red[3];
      __threadfence();
      last = (atomicAdd(cnt, 1) == 95);
    }
    __syncthreads();
  }
  if (!last) return;
  __threadfence();
  float v = 0.f;
  if (tid < 64) v = ps[tid] * (1.0f/65536.0f);
  else if (tid < 96) v = ps[tid] * (1.0f/32768.0f);
  for (int off=32; off; off>>=1) v += __shfl_xor(v,off);
  __syncthreads();
  if ((tid&63)==0) red[tid>>6]=v;
  __syncthreads();
  if (tid==0) out[0] = red[0]+red[1]+red[2]+red[3];
}

// ---------------- launch ----------------
extern "C" void kernel_launch(void* const* d_in, const int* in_sizes, int n_in,
                              void* d_out, int out_size, void* d_ws, size_t ws_size,
                              hipStream_t stream)
{
  (void)in_sizes; (void)n_in; (void)out_size;
  const float* in_pc = (const float*)d_in[0];
  const float* w1   = (const float*)d_in[1];
  const float* b1   = (const float*)d_in[2];
  const float* w2   = (const float*)d_in[3];
  const float* b2   = (const float*)d_in[4];
  const float* w3   = (const float*)d_in[5];
  const float* b3   = (const float*)d_in[6];
  const float* wenc = (const float*)d_in[7];
  const float* benc = (const float*)d_in[8];
  const float* wf1  = (const float*)d_in[9];
  const float* bfc1 = (const float*)d_in[10];
  const float* wf2  = (const float*)d_in[11];
  const float* bfc2 = (const float*)d_in[12];
  const float* wf3  = (const float*)d_in[13];
  const float* bfc3 = (const float*)d_in[14];
  const float* lng  = (const float*)d_in[15];
  const float* lnb  = (const float*)d_in[16];
  float* out = (float*)d_out;

  bool big = ws_size >= (size_t)(H2_BYTES + 2*1024*1024);
  char* ws = (char*)d_ws;
  unsigned short* h2b = (unsigned short*)ws;
  char* small = ws + (big ? H2_BYTES : 0);

  unsigned* gfeatU = (unsigned*)(small + OFF_GFEAT);
  float* pooled = (float*)(small + OFF_POOL);
  float* gcon = (float*)(small + OFF_GCON);
  float* emb  = (float*)(small + OFF_EMB);
  float* hd1  = (float*)(small + OFF_HD1);
  float* hd2  = (float*)(small + OFF_HD2);
  float* h3   = (float*)(small + OFF_H3);
  float* opc  = (float*)(small + OFF_OPC);
  unsigned* d1m = (unsigned*)(small + OFF_D1M);
  unsigned* d2m = (unsigned*)(small + OFF_D2M);
  float* ps   = (float*)(small + OFF_PS);
  unsigned short* w3b = (unsigned short*)(small + OFF_W3BF);
  int* cnt = (int*)(small + OFF_CNT);

  hipMemsetAsync(small + OFF_GFEAT, 0, 8192 + 65536, stream);      // gfeat + pooled = 0
  hipMemsetAsync(small + OFF_D1M, 0x7F, 262144 + 131072, stream);  // d1m + d2m ~ +inf

  if (big){
    conv12_mfma<<<1024, 256, 0, stream>>>(in_pc, w1, b1, w2, b2, out, h2b, gfeatU,
                                          w3, (unsigned*)w3b);
    bcast_gcon<<<8196, 256, 0, stream>>>(gfeatU, out, w3, b3, gcon);
    conv3_pool<<<dim3(32,16), 512, 0, stream>>>(h2b, w3b, gcon, (unsigned*)pooled);
  } else {
    conv12_f32<<<dim3(256,4), 256, 0, stream>>>(in_pc, w1, b1, w2, b2, out, gfeatU);
    bcast_gcon<<<8196, 256, 0, stream>>>(gfeatU, out, w3, b3, gcon);
    conv3n<<<2048, 256, 0, stream>>>(out, gfeatU, w3, b3, (unsigned*)pooled);
  }
  fc_wave16<false><<<64,   256, 0, stream>>>(pooled, wenc, benc, emb, out + OUT_EMB, 1024, 256);
  fc_wave16<true ><<<128,  256, 0, stream>>>(emb, wf1, bfc1, hd1, nullptr, 256, 512);
  fc_wave16<true ><<<256,  256, 0, stream>>>(hd1, wf2, bfc2, hd2, nullptr, 512, 1024);
  fc_wave16<false><<<1536, 256, 0, stream>>>(hd2, wf3, bfc3, h3, nullptr, 1024, 6144);
  lnorm<<<16, 256, 0, stream>>>(h3, lng, lnb, opc, out + OUT_OPC, cnt);
  chamfer_all<<<4096, 256, 0, stream>>>(in_pc, opc, d1m, d2m);
  sum_loss<<<96, 256, 0, stream>>>(d1m, d2m, ps, cnt, out + OUT_LOSS);
}

// Round 14
// 163.773 us; speedup vs baseline: 1.4509x; 1.0145x over previous
//
#include <hip/hip_runtime.h>

// output element offsets (f32 elements)
#define OUT_X0   0
#define OUT_EMB  16777216
#define OUT_OPC  16781312
#define OUT_LOSS 16879616

// small-buffer byte offsets (relative to `small` base)
#define OFF_GFEAT 0            // 8192     u32 float-bits [16][128]
#define OFF_POOL  8192         // 65536    u32 float-bits [16][1024]
#define OFF_GCON  73728        // 65536    f32 [16][1024]
#define OFF_EMB   139264       // 16384    f32 [16][256]
#define OFF_HD1   155648       // 32768    f32 [16][512]
#define OFF_HD2   188416       // 65536    f32 [16][1024]
#define OFF_H3    253952       // 393216   f32 [16][6144]
#define OFF_OPC   647168       // 393216   f32 [16][6144]
#define OFF_D1M   1040384      // 262144   u32 [16][4096]
#define OFF_D2M   1302528      // 131072   u32 [16][2048]
#define OFF_PS    1433600      // 384      f32 [96]
#define OFF_W3BF  1433984      // 524288   bf16 w3 [1024][256]
#define OFF_CNT   1958272      // 4        int counter
#define H2_BYTES  (16u*1024*1024)   // bf16 h2 [65536][128] at ws+0 (big path)

typedef short short8 __attribute__((ext_vector_type(8)));
typedef float f32x4  __attribute__((ext_vector_type(4)));

__device__ __forceinline__ unsigned short f2bf(float f){
  unsigned u = __float_as_uint(f);
  return (unsigned short)((u + 0x7FFFu + ((u >> 16) & 1u)) >> 16);
}

// ---- init: gfeat+pooled = 0, d1m+d2m = 0x7F..., cnt = 0 (replaces 2 memset nodes) ----
__global__ __launch_bounds__(256) void init_k(char* __restrict__ small)
{
  int i = blockIdx.x*256 + threadIdx.x;
  uint4* z = (uint4*)(small + OFF_GFEAT);   // 73728 B = 4608 uint4
  uint4* d = (uint4*)(small + OFF_D1M);     // 393216 B = 24576 uint4
  if (i < 4608) z[i] = make_uint4(0u,0u,0u,0u);
  int j = i - 4608;
  if (j >= 0 && j < 24576)
    d[j] = make_uint4(0x7F7F7F7Fu,0x7F7F7F7Fu,0x7F7F7F7Fu,0x7F7F7F7Fu);
  if (i == 29184) *(int*)(small + OFF_CNT) = 0;
}

// ------- conv1+conv2 via MFMA: C[ch][pt]; x0 f32 + h2 bf16 + gfeat. -------
// blocks 0..511: conv (16 b x 32 pt-tiles of 128). blocks 512..1023: w3 cvt.
__global__ __launch_bounds__(256) void conv12_mfma(
    const float* __restrict__ in_pc,
    const float* __restrict__ w1, const float* __restrict__ b1,
    const float* __restrict__ w2, const float* __restrict__ b2,
    float* __restrict__ x0, unsigned short* __restrict__ h2b,
    unsigned* __restrict__ gfeatU,
    const float* __restrict__ w3, unsigned* __restrict__ w3bf)
{
  __shared__ unsigned short w2s[8192];   // [128 ch][64 c] bf16, XOR-swizzled
  __shared__ unsigned short h1s[8192];   // [128 pt][64 c] bf16, XOR-swizzled
  __shared__ float b2s[128];
  __shared__ unsigned gmax[128];
  int tid = threadIdx.x, bid = blockIdx.x;
  if (bid >= 512){   // folded w3 f32->bf16 pre-pass: 512*256 float2 = 131072
    int i = (bid-512)*256 + tid;
    float2 v = ((const float2*)w3)[i];
    w3bf[i] = (unsigned)f2bf(v.x) | ((unsigned)f2bf(v.y)<<16);
    return;
  }
  int b = bid >> 5;
  int nt0 = (bid & 31)*128;
  // stage w2 -> bf16 LDS (2048 float4)
  for (int i = tid; i < 2048; i += 256){
    int ch = i >> 4, q = i & 15;
    float4 v = ((const float4*)w2)[i];
    unsigned lo = (unsigned)f2bf(v.x) | ((unsigned)f2bf(v.y)<<16);
    unsigned hi = (unsigned)f2bf(v.z) | ((unsigned)f2bf(v.w)<<16);
    int byte = (ch*128 + q*8) ^ ((ch&7)<<4);
    *(uint2*)((char*)w2s + byte) = make_uint2(lo, hi);
  }
  if (tid < 128){ b2s[tid] = b2[tid]; gmax[tid] = 0u; }
  { // h1: 2 threads per point, 32 channels each
    int pt = tid & 127;
    int qb = (tid >> 7) * 16;       // channel-pair base: 0 or 16
    int idx = b*4096 + nt0 + pt;
    const float* p = in_pc + (size_t)idx*3;
    float px=p[0], py=p[1], pz=p[2];
    unsigned hp[16];
    #pragma unroll
    for (int q=0;q<16;q++){
      int c = (qb + q)*2;
      float v0 = fmaxf(fmaf(w1[c*3  ],px, fmaf(w1[c*3+1],py, fmaf(w1[c*3+2],pz, b1[c  ]))), 0.f);
      float v1 = fmaxf(fmaf(w1[c*3+3],px, fmaf(w1[c*3+4],py, fmaf(w1[c*3+5],pz, b1[c+1]))), 0.f);
      hp[q] = (unsigned)f2bf(v0) | ((unsigned)f2bf(v1)<<16);
    }
    #pragma unroll
    for (int t=0;t<4;t++){
      int byte = (pt*128 + qb*4 + t*16) ^ ((pt&7)<<4);
      *(uint4*)((char*)h1s + byte) = make_uint4(hp[t*4],hp[t*4+1],hp[t*4+2],hp[t*4+3]);
    }
  }
  __syncthreads();
  int lane = tid & 63, w = tid >> 6;
  int g = lane >> 4, p15 = lane & 15;
  f32x4 acc[8][2] = {};
  #pragma unroll
  for (int ks=0; ks<2; ks++){
    int kb = (ks*32 + g*8)*2;
    short8 bfr[2];
    #pragma unroll
    for (int nf=0;nf<2;nf++){
      int pt = w*32 + nf*16 + p15;
      bfr[nf] = *(const short8*)((const char*)h1s + ((pt*128 + kb) ^ ((pt&7)<<4)));
    }
    #pragma unroll
    for (int mf=0;mf<8;mf++){
      int ch = mf*16 + p15;
      short8 af = *(const short8*)((const char*)w2s + ((ch*128 + kb) ^ ((ch&7)<<4)));
      acc[mf][0] = __builtin_amdgcn_mfma_f32_16x16x32_bf16(af, bfr[0], acc[mf][0], 0,0,0);
      acc[mf][1] = __builtin_amdgcn_mfma_f32_16x16x32_bf16(af, bfr[1], acc[mf][1], 0,0,0);
    }
  }
  // epilogue: +bias, relu, x0 [ch][n] f32, h2 [n][ch] bf16, gfeat max
  int n_base = nt0 + w*32;
  #pragma unroll
  for (int mf=0; mf<8; mf++){
    int ch0 = mf*16 + g*4;
    float bias[4];
    #pragma unroll
    for (int j=0;j<4;j++) bias[j] = b2s[ch0+j];
    float vm[4] = {0.f,0.f,0.f,0.f};
    #pragma unroll
    for (int nf=0; nf<2; nf++){
      int n = n_base + nf*16 + p15;
      float v[4];
      #pragma unroll
      for (int j=0;j<4;j++){
        v[j] = fmaxf(acc[mf][nf][j] + bias[j], 0.f);
        vm[j] = fmaxf(vm[j], v[j]);
        x0[((size_t)(b*256 + ch0 + j))*4096 + n] = v[j];
      }
      unsigned lo = (unsigned)f2bf(v[0]) | ((unsigned)f2bf(v[1])<<16);
      unsigned hi = (unsigned)f2bf(v[2]) | ((unsigned)f2bf(v[3])<<16);
      *(uint2*)&h2b[((size_t)(b*4096 + n))*128 + ch0] = make_uint2(lo, hi);
    }
    #pragma unroll
    for (int j=0;j<4;j++){
      float m = vm[j];
      m = fmaxf(m, __shfl_xor(m,1));
      m = fmaxf(m, __shfl_xor(m,2));
      m = fmaxf(m, __shfl_xor(m,4));
      m = fmaxf(m, __shfl_xor(m,8));
      if (p15==0) atomicMax(&gmax[ch0+j], __float_as_uint(m));
    }
  }
  __syncthreads();
  if (tid < 128) atomicMax(&gfeatU[b*128 + tid], gmax[tid]);
}

// ---- gfeat bcast (8192 blocks) + gcon (4 blocks) ----
__global__ __launch_bounds__(256) void bcast_gcon(
    const unsigned* __restrict__ gfeatU, float* __restrict__ x0,
    const float* __restrict__ w3, const float* __restrict__ b3,
    float* __restrict__ gcon)
{
  __shared__ float gf[2048];
  int tid = threadIdx.x;
  if (blockIdx.x < 8192){
    unsigned U = blockIdx.x*256 + tid;
    int n4 = U & 1023, c = (U >> 10) & 127, b = U >> 17;
    float g = __uint_as_float(gfeatU[b*128+c]);
    float4 v = {g,g,g,g};
    ((float4*)x0)[(((size_t)b*256 + 128 + c)*4096)/4 + n4] = v;
  } else {
    for (int i=tid;i<2048;i+=256) gf[i] = __uint_as_float(gfeatU[i]);
    __syncthreads();
    int o = (blockIdx.x - 8192)*256 + tid;
    float bias = b3[o];
    float acc[16];
    #pragma unroll
    for (int b=0;b<16;b++) acc[b]=bias;
    for (int c=0;c<128;c++){
      float wv = w3[(size_t)o*256 + 128 + c];
      #pragma unroll
      for (int b=0;b<16;b++) acc[b] += gf[b*128+c]*wv;
    }
    #pragma unroll
    for (int b=0;b<16;b++) gcon[b*1024+o] = acc[b];
  }
}

// ------- conv3 MFMA GEMM: 128m tile, 8x128o steps; 64KB LDS -> 2 blocks/CU -------
__global__ __launch_bounds__(512) void conv3_pool(
    const unsigned short* __restrict__ h2b, const unsigned short* __restrict__ w3b,
    const float* __restrict__ gcon, unsigned* __restrict__ pooled)
{
  __shared__ unsigned short Al[128*128];
  __shared__ unsigned short Bl[128*128];
  int mt = blockIdx.x, b = blockIdx.y;   // mt < 32
  int tid = threadIdx.x;
  { // stage A: 128 rows x 128 k
    const uint4* src = (const uint4*)(h2b + ((size_t)b*4096 + mt*128)*128);
    #pragma unroll
    for (int i=0;i<4;i++){
      int idx = i*512 + tid;
      int r = idx>>4, kc = idx&15;
      uint4 v = src[idx];
      int byte = (r*256 + kc*16) ^ ((r&7)<<4);
      *(uint4*)((char*)Al + byte) = v;
    }
  }
  int lane = tid & 63, wid = tid >> 6;
  int wm = wid >> 2, wn = wid & 3;       // 2x4 waves over 128m x 128o
  int mbase = wm*64, nbase = wn*32;
  for (int nt=0; nt<8; nt++){
    if (nt) __syncthreads();
    { // stage B: 128 cols x 128 k
      #pragma unroll
      for (int i=0;i<4;i++){
        int idx = i*512 + tid;
        int c = idx>>4, kc = idx&15;
        uint4 v = *(const uint4*)(w3b + ((size_t)(nt*128+c)*256 + kc*8));
        int byte = (c*256 + kc*16) ^ ((c&7)<<4);
        *(uint4*)((char*)Bl + byte) = v;
      }
    }
    __syncthreads();
    f32x4 acc[4][2] = {};
    #pragma unroll
    for (int ks=0;ks<4;ks++){
      int kb = (ks*32 + (lane>>4)*8)*2;
      short8 af[4], bfr[2];
      #pragma unroll
      for (int mi=0;mi<4;mi++){
        int row = mbase + mi*16 + (lane&15);
        af[mi] = *(const short8*)((const char*)Al + ((row*256 + kb) ^ ((row&7)<<4)));
      }
      #pragma unroll
      for (int ni=0;ni<2;ni++){
        int col = nbase + ni*16 + (lane&15);
        bfr[ni] = *(const short8*)((const char*)Bl + ((col*256 + kb) ^ ((col&7)<<4)));
      }
      #pragma unroll
      for (int mi=0;mi<4;mi++){
        #pragma unroll
        for (int ni=0;ni<2;ni++)
          acc[mi][ni] = __builtin_amdgcn_mfma_f32_16x16x32_bf16(af[mi], bfr[ni], acc[mi][ni], 0,0,0);
      }
    }
    #pragma unroll
    for (int ni=0;ni<2;ni++){
      int o = nt*128 + nbase + ni*16 + (lane&15);
      float g = gcon[b*1024 + o];
      float m = 0.f;
      #pragma unroll
      for (int mi=0;mi<4;mi++){
        f32x4 a = acc[mi][ni];
        #pragma unroll
        for (int r=0;r<4;r++){ float v = a[r]+g; m = fmaxf(m, v); }
      }
      m = fmaxf(m, 0.f);
      m = fmaxf(m, __shfl_xor(m, 16));
      m = fmaxf(m, __shfl_xor(m, 32));
      if (lane < 16) atomicMax(&pooled[(size_t)b*1024+o], __float_as_uint(m));
    }
  }
}

// ---- fallback (small ws): conv12 writes x0 f32 directly + gfeat ----
__global__ __launch_bounds__(256) void conv12_f32(
    const float* __restrict__ in_pc,
    const float* __restrict__ w1, const float* __restrict__ b1,
    const float* __restrict__ w2, const float* __restrict__ b2,
    float* __restrict__ x0, unsigned* __restrict__ gfeatU)
{
  __shared__ unsigned gmax[32];
  int tid = threadIdx.x;
  if (tid < 32) gmax[tid] = 0u;
  __syncthreads();
  int idx = blockIdx.x*256 + tid;
  int b = idx >> 12, n = idx & 4095;
  int gy = blockIdx.y;
  int lane = tid & 63;
  const float* p = in_pc + (size_t)idx*3;
  float px=p[0], py=p[1], pz=p[2];
  float h1[64];
  #pragma unroll
  for (int c=0;c<64;c++)
    h1[c] = fmaxf(w1[c*3]*px + w1[c*3+1]*py + w1[c*3+2]*pz + b1[c], 0.f);
  #pragma unroll
  for (int j=0;j<32;j++){
    int o = gy*32 + j;
    float a = b2[o];
    #pragma unroll
    for (int c=0;c<64;c++) a += w2[o*64+c]*h1[c];
    a = fmaxf(a, 0.f);
    x0[((size_t)b*256 + o)*4096 + n] = a;
    float m = a;
    #pragma unroll
    for (int off=32; off; off>>=1) m = fmaxf(m, __shfl_xor(m, off));
    if (lane==0) atomicMax(&gmax[j], __float_as_uint(m));
  }
  __syncthreads();
  if (tid < 32) atomicMax(&gfeatU[b*128 + gy*32 + tid], gmax[tid]);
}

// ---- fallback conv3 ----
__global__ __launch_bounds__(256) void conv3n(
    const float* __restrict__ x0, const unsigned* __restrict__ gfeatU,
    const float* __restrict__ w3, const float* __restrict__ b3,
    unsigned* __restrict__ pooled)
{
  __shared__ float wrow[8][256];
  int b = blockIdx.x >> 7, og = (blockIdx.x & 127)*8, tid = threadIdx.x;
  for (int i=tid;i<2048;i+=256){ int j=i>>8, c=i&255; wrow[j][c]=w3[(size_t)(og+j)*256+c]; }
  __syncthreads();
  float gconst[8];
  #pragma unroll
  for (int j=0;j<8;j++){
    float g = b3[og+j];
    for (int c=0;c<128;c++) g += __uint_as_float(gfeatU[b*128+c])*wrow[j][128+c];
    gconst[j] = g;
  }
  const float* xb = x0 + (size_t)b*256*4096;
  float m[8];
  #pragma unroll
  for (int j=0;j<8;j++) m[j]=0.f;
  for (int n=tid;n<4096;n+=256){
    float v[8];
    #pragma unroll
    for (int j=0;j<8;j++) v[j]=gconst[j];
    for (int c=0;c<128;c++){
      float xv = xb[(size_t)c*4096 + n];
      #pragma unroll
      for (int j=0;j<8;j++) v[j] += xv*wrow[j][c];
    }
    #pragma unroll
    for (int j=0;j<8;j++) m[j] = fmaxf(m[j], v[j]);
  }
  #pragma unroll
  for (int j=0;j<8;j++){
    float v = m[j];
    for (int off=32; off; off>>=1) v = fmaxf(v, __shfl_xor(v, off));
    if ((tid&63)==0) atomicMax(&pooled[(size_t)b*1024+og+j], __float_as_uint(v));
  }
}

// ------- fc: one wave per output o, all 16 batches in registers -------
template<bool RELU>
__global__ __launch_bounds__(256) void fc_wave16(
    const float* __restrict__ A, const float* __restrict__ W,
    const float* __restrict__ bias, float* __restrict__ out,
    float* __restrict__ out2, int K, int O)
{
  int lane = threadIdx.x & 63, w = threadIdx.x >> 6;
  int o = blockIdx.x*4 + w;
  const float* Wr = W + (size_t)o*K;
  float acc[16];
  #pragma unroll
  for (int b=0;b<16;b++) acc[b]=0.f;
  for (int k = lane*4; k < K; k += 256){
    float4 wv = *(const float4*)&Wr[k];
    #pragma unroll
    for (int b=0;b<16;b++){
      float4 av = *(const float4*)&A[(size_t)b*K + k];
      acc[b] += wv.x*av.x + wv.y*av.y + wv.z*av.z + wv.w*av.w;
    }
  }
  #pragma unroll
  for (int b=0;b<16;b++){
    float v = acc[b];
    #pragma unroll
    for (int off=32; off; off>>=1) v += __shfl_xor(v, off);
    if (lane==0){
      v += bias[o];
      if (RELU) v = fmaxf(v, 0.f);
      out[(size_t)b*O+o] = v;
      if (out2) out2[(size_t)b*O+o] = v;
    }
  }
}

// ---------------- LayerNorm (also zeroes the sum counter) ----------------
__global__ __launch_bounds__(256) void lnorm(
    const float* __restrict__ h3, const float* __restrict__ g,
    const float* __restrict__ be, float* __restrict__ outf,
    float* __restrict__ outb, int* __restrict__ cnt)
{
  int b = blockIdx.x, tid = threadIdx.x;
  if (b==0 && tid==0) *cnt = 0;
  const float* x = h3 + b*6144;
  float s=0.f, s2=0.f;
  for (int i=tid;i<6144;i+=256){ float v=x[i]; s+=v; s2+=v*v; }
  for (int off=32; off; off>>=1){ s += __shfl_xor(s,off); s2 += __shfl_xor(s2,off); }
  __shared__ float red[8];
  int lane = tid&63, wid = tid>>6;
  if (lane==0){ red[wid]=s; red[4+wid]=s2; }
  __syncthreads();
  s  = red[0]+red[1]+red[2]+red[3];
  s2 = red[4]+red[5]+red[6]+red[7];
  float mu  = s * (1.f/6144.f);
  float var = s2 * (1.f/6144.f) - mu*mu;
  float inv = rsqrtf(var + 1e-5f);
  for (int i=tid;i<6144;i+=256){
    float v = (x[i]-mu)*inv*g[i] + be[i];
    outf[b*6144+i] = v;
    outb[b*6144+i] = v;
  }
}

// ---- chamfer: stage (-2x,-2y,-2z,q^2); 3 FMA + 1 min per pair ----
__global__ __launch_bounds__(256) void chamfer_all(
    const float* __restrict__ in_pc, const float* __restrict__ opc,
    unsigned* __restrict__ d1m, unsigned* __restrict__ d2m)
{
  __shared__ float sX[256], sY[256], sZ[256], sQ[256];
  int bid = blockIdx.x, tid = threadIdx.x;
  const float* stage;
  const float* qry;
  unsigned* outp;
  if (bid < 2048){
    int xt = bid & 15, b = (bid >> 4) & 15, mt = bid >> 8;
    stage = opc + b*6144 + mt*768;
    qry   = in_pc + ((size_t)b*4096 + xt*256 + tid)*3;
    outp  = d1m + b*4096 + xt*256 + tid;
  } else {
    int r = bid - 2048;
    int xt = r & 7, b = (r >> 3) & 15, nt = r >> 7;
    stage = in_pc + ((size_t)b*4096 + nt*256)*3;
    qry   = opc + b*6144 + (xt*256 + tid)*3;
    outp  = d2m + b*2048 + xt*256 + tid;
  }
  {
    const float* S = stage + tid*3;
    float x=S[0], y=S[1], z=S[2];
    sX[tid]=-2.f*x; sY[tid]=-2.f*y; sZ[tid]=-2.f*z; sQ[tid]=x*x+y*y+z*z;
  }
  __syncthreads();
  float qx=qry[0], qy=qry[1], qz=qry[2];
  float p2 = qx*qx + qy*qy + qz*qz;
  float ma=3.0e38f, mb=3.0e38f, mc=3.0e38f, md=3.0e38f;
  #pragma unroll 4
  for (int i=0;i<64;i++){
    float4 X = *(const float4*)&sX[i*4];
    float4 Y = *(const float4*)&sY[i*4];
    float4 Z = *(const float4*)&sZ[i*4];
    float4 Q = *(const float4*)&sQ[i*4];
    float t;
    t = fmaf(qx,X.x, fmaf(qy,Y.x, fmaf(qz,Z.x, Q.x))); ma = fminf(ma,t);
    t = fmaf(qx,X.y, fmaf(qy,Y.y, fmaf(qz,Z.y, Q.y))); mb = fminf(mb,t);
    t = fmaf(qx,X.z, fmaf(qy,Y.z, fmaf(qz,Z.z, Q.z))); mc = fminf(mc,t);
    t = fmaf(qx,X.w, fmaf(qy,Y.w, fmaf(qz,Z.w, Q.w))); md = fminf(md,t);
  }
  float d = fmaxf(p2 + fminf(fminf(ma,mb), fminf(mc,md)), 0.f);
  atomicMin(outp, __float_as_uint(d));
}

// ---- fused deterministic loss reduction (96 partials + last-block finish) ----
__global__ __launch_bounds__(256) void sum_loss(
    const unsigned* __restrict__ d1m, const unsigned* __restrict__ d2m,
    float* __restrict__ ps, int* __restrict__ cnt, float* __restrict__ out)
{
  int bid = blockIdx.x, tid = threadIdx.x;
  __shared__ float red[4];
  __shared__ int last;
  {
    const unsigned* src = (bid<64) ? (d1m + bid*1024) : (d2m + (size_t)(bid-64)*1024);
    float s = 0.f;
    for (int i=tid;i<1024;i+=256) s += __uint_as_float(src[i]);
    for (int off=32; off; off>>=1) s += __shfl_xor(s,off);
    if ((tid&63)==0) red[tid>>6]=s;
    __syncthreads();
    if (tid==0){
      ps[bid] = red[0]+red[1]+red[2]+red[3];
      __threadfence();
      last = (atomicAdd(cnt, 1) == 95);
    }
    __syncthreads();
  }
  if (!last) return;
  __threadfence();
  float v = 0.f;
  if (tid < 64) v = ps[tid] * (1.0f/65536.0f);
  else if (tid < 96) v = ps[tid] * (1.0f/32768.0f);
  for (int off=32; off; off>>=1) v += __shfl_xor(v,off);
  __syncthreads();
  if ((tid&63)==0) red[tid>>6]=v;
  __syncthreads();
  if (tid==0) out[0] = red[0]+red[1]+red[2]+red[3];
}

// ---------------- launch ----------------
extern "C" void kernel_launch(void* const* d_in, const int* in_sizes, int n_in,
                              void* d_out, int out_size, void* d_ws, size_t ws_size,
                              hipStream_t stream)
{
  (void)in_sizes; (void)n_in; (void)out_size;
  const float* in_pc = (const float*)d_in[0];
  const float* w1   = (const float*)d_in[1];
  const float* b1   = (const float*)d_in[2];
  const float* w2   = (const float*)d_in[3];
  const float* b2   = (const float*)d_in[4];
  const float* w3   = (const float*)d_in[5];
  const float* b3   = (const float*)d_in[6];
  const float* wenc = (const float*)d_in[7];
  const float* benc = (const float*)d_in[8];
  const float* wf1  = (const float*)d_in[9];
  const float* bfc1 = (const float*)d_in[10];
  const float* wf2  = (const float*)d_in[11];
  const float* bfc2 = (const float*)d_in[12];
  const float* wf3  = (const float*)d_in[13];
  const float* bfc3 = (const float*)d_in[14];
  const float* lng  = (const float*)d_in[15];
  const float* lnb  = (const float*)d_in[16];
  float* out = (float*)d_out;

  bool big = ws_size >= (size_t)(H2_BYTES + 2*1024*1024);
  char* ws = (char*)d_ws;
  unsigned short* h2b = (unsigned short*)ws;
  char* small = ws + (big ? H2_BYTES : 0);

  unsigned* gfeatU = (unsigned*)(small + OFF_GFEAT);
  float* pooled = (float*)(small + OFF_POOL);
  float* gcon = (float*)(small + OFF_GCON);
  float* emb  = (float*)(small + OFF_EMB);
  float* hd1  = (float*)(small + OFF_HD1);
  float* hd2  = (float*)(small + OFF_HD2);
  float* h3   = (float*)(small + OFF_H3);
  float* opc  = (float*)(small + OFF_OPC);
  unsigned* d1m = (unsigned*)(small + OFF_D1M);
  unsigned* d2m = (unsigned*)(small + OFF_D2M);
  float* ps   = (float*)(small + OFF_PS);
  unsigned short* w3b = (unsigned short*)(small + OFF_W3BF);
  int* cnt = (int*)(small + OFF_CNT);

  init_k<<<115, 256, 0, stream>>>(small);

  if (big){
    conv12_mfma<<<1024, 256, 0, stream>>>(in_pc, w1, b1, w2, b2, out, h2b, gfeatU,
                                          w3, (unsigned*)w3b);
    bcast_gcon<<<8196, 256, 0, stream>>>(gfeatU, out, w3, b3, gcon);
    conv3_pool<<<dim3(32,16), 512, 0, stream>>>(h2b, w3b, gcon, (unsigned*)pooled);
  } else {
    conv12_f32<<<dim3(256,4), 256, 0, stream>>>(in_pc, w1, b1, w2, b2, out, gfeatU);
    bcast_gcon<<<8196, 256, 0, stream>>>(gfeatU, out, w3, b3, gcon);
    conv3n<<<2048, 256, 0, stream>>>(out, gfeatU, w3, b3, (unsigned*)pooled);
  }
  fc_wave16<false><<<64,   256, 0, stream>>>(pooled, wenc, benc, emb, out + OUT_EMB, 1024, 256);
  fc_wave16<true ><<<128,  256, 0, stream>>>(emb, wf1, bfc1, hd1, nullptr, 256, 512);
  fc_wave16<true ><<<256,  256, 0, stream>>>(hd1, wf2, bfc2, hd2, nullptr, 512, 1024);
  fc_wave16<false><<<1536, 256, 0, stream>>>(hd2, wf3, bfc3, h3, nullptr, 1024, 6144);
  lnorm<<<16, 256, 0, stream>>>(h3, lng, lnb, opc, out + OUT_OPC, cnt);
  chamfer_all<<<4096, 256, 0, stream>>>(in_pc, opc, d1m, d2m);
  sum_loss<<<96, 256, 0, stream>>>(d1m, d2m, ps, cnt, out + OUT_LOSS);
}